// Round 10
// baseline (1406.080 us; speedup 1.0000x reference)
//
#include <hip/hip_runtime.h>
#include <cmath>
#include <cstdint>

#define D_MODEL 512
#define NH 8
#define DH 64

static inline int ceil_div(int a, int b) { return (a + b - 1) / b; }

typedef __attribute__((ext_vector_type(8))) short short8;
typedef __attribute__((ext_vector_type(4))) float floatx4;

// fp32 -> bf16 (RNE)
__device__ __forceinline__ unsigned short f2bf(float f) {
  uint32_t u = __float_as_uint(f);
  uint32_t r = (u + 0x7fffu + ((u >> 16) & 1u)) >> 16;
  return (unsigned short)r;
}
__device__ __forceinline__ float bf2f(unsigned short s) {
  return __uint_as_float(((uint32_t)s) << 16);
}

// ---------------- threefry2x32 (JAX-exact) ----------------
#define TF_ROTL(x, r) (((x) << (r)) | ((x) >> (32 - (r))))

__host__ __device__ inline void threefry2x32(uint32_t k0, uint32_t k1,
                                             uint32_t x0, uint32_t x1,
                                             uint32_t* o0, uint32_t* o1) {
  uint32_t ks2 = k0 ^ k1 ^ 0x1BD11BDAu;
  x0 += k0; x1 += k1;
#define TF_R4(a, b, c, d)                                    \
  x0 += x1; x1 = TF_ROTL(x1, a); x1 ^= x0;                   \
  x0 += x1; x1 = TF_ROTL(x1, b); x1 ^= x0;                   \
  x0 += x1; x1 = TF_ROTL(x1, c); x1 ^= x0;                   \
  x0 += x1; x1 = TF_ROTL(x1, d); x1 ^= x0;
  TF_R4(13, 15, 26, 6);  x0 += k1;  x1 += ks2 + 1u;
  TF_R4(17, 29, 16, 24); x0 += ks2; x1 += k0 + 2u;
  TF_R4(13, 15, 26, 6);  x0 += k0;  x1 += k1 + 3u;
  TF_R4(17, 29, 16, 24); x0 += k1;  x1 += ks2 + 4u;
  TF_R4(13, 15, 26, 6);  x0 += ks2; x1 += k0 + 5u;
#undef TF_R4
  *o0 = x0; *o1 = x1;
}

// ---------------- upfront weight casts (multi-source, batched) -------------
__global__ __launch_bounds__(256) void cast3_qkv_kernel(
    const float* __restrict__ s0, const float* __restrict__ s1,
    const float* __restrict__ s2, unsigned short* __restrict__ dst) {
  int sel = blockIdx.x / 768, bb = blockIdx.x % 768;
  int i = (bb * 256 + threadIdx.x) * 4;  // < 786432
  const float* s = (sel == 0) ? s0 : (sel == 1) ? s1 : s2;
  float4 v = *(const float4*)(s + i);
  ushort4 o;
  o.x = f2bf(v.x); o.y = f2bf(v.y); o.z = f2bf(v.z); o.w = f2bf(v.w);
  int layer = i >> 18, off = i & 262143;
  *(ushort4*)(dst + (size_t)layer * 786432 + sel * 262144 + off) = o;
}

__global__ __launch_bounds__(256) void cast3_flat_kernel(
    const float* __restrict__ s0, const float* __restrict__ s1,
    const float* __restrict__ s2, unsigned short* __restrict__ dst) {
  int sel = blockIdx.x / 768, bb = blockIdx.x % 768;
  int i = (bb * 256 + threadIdx.x) * 4;
  const float* s = (sel == 0) ? s0 : (sel == 1) ? s1 : s2;
  float4 v = *(const float4*)(s + i);
  ushort4 o;
  o.x = f2bf(v.x); o.y = f2bf(v.y); o.z = f2bf(v.z); o.w = f2bf(v.w);
  *(ushort4*)(dst + (size_t)sel * 786432 + i) = o;
}

// conv weights permute-cast: w[m][n][c][k] -> dst[m][n][k*512 + c]
__global__ __launch_bounds__(256) void cast_cvperm_kernel(
    const float* __restrict__ src, unsigned short* __restrict__ dst) {
  int o = blockIdx.x * 256 + threadIdx.x;  // < 2*786432
  int m = o / 786432, rem = o % 786432;
  int n = rem / 1536, q = rem % 1536;
  int k = q >> 9, c = q & 511;
  dst[o] = f2bf(src[(size_t)m * 786432 + n * 1536 + c * 3 + k]);
}

// ---------------- embedding + pos encoding, dual fp32/bf16 out ------------
__global__ __launch_bounds__(256) void embed_kernel(
    const float* __restrict__ x_enc, const float* __restrict__ emb_w,
    float* __restrict__ x, unsigned short* __restrict__ xb, int B, int L) {
  int i = blockIdx.x * 256 + threadIdx.x;
  int total = B * L * D_MODEL;
  if (i >= total) return;
  int d = i % D_MODEL;
  int l = (i / D_MODEL) % L;
  int b = i / (D_MODEL * L);
  int lm = (l == 0) ? (L - 1) : (l - 1);
  int lp = (l == L - 1) ? 0 : (l + 1);
  const float* w = emb_w + d * 6;
  const float* xb_in = x_enc + (size_t)b * L * 2;
  float acc = 0.f;
  acc += xb_in[lm * 2 + 0] * w[0] + xb_in[l * 2 + 0] * w[1] + xb_in[lp * 2 + 0] * w[2];
  acc += xb_in[lm * 2 + 1] * w[3] + xb_in[l * 2 + 1] * w[4] + xb_in[lp * 2 + 1] * w[5];
  int j = d >> 1;
  const float coef = -0.017988946039015985f;  // -ln(10000)/512
  float div = expf((float)(2 * j) * coef);
  float ang = (float)l * div;
  float pe = (d & 1) ? cosf(ang) : sinf(ang);
  float v = acc + pe;
  x[i] = v;
  xb[i] = f2bf(v);
}

// ---------------- layer norm over D=512 (plain + dual-output) -------------
__global__ __launch_bounds__(256) void ln_kernel(
    const float* __restrict__ in, const float* __restrict__ g,
    const float* __restrict__ b, float* __restrict__ out) {
  int row = blockIdx.x;
  int t = threadIdx.x;
  const float* xr = in + (size_t)row * D_MODEL;
  float v0 = xr[t], v1 = xr[t + 256];
  __shared__ float red[256];
  red[t] = v0 + v1;
  __syncthreads();
  for (int s = 128; s > 0; s >>= 1) { if (t < s) red[t] += red[t + s]; __syncthreads(); }
  float mean = red[0] * (1.0f / 512.0f);
  __syncthreads();
  float d0 = v0 - mean, d1 = v1 - mean;
  red[t] = d0 * d0 + d1 * d1;
  __syncthreads();
  for (int s = 128; s > 0; s >>= 1) { if (t < s) red[t] += red[t + s]; __syncthreads(); }
  float var = red[0] * (1.0f / 512.0f);
  float rstd = 1.0f / sqrtf(var + 1e-5f);
  float* outr = out + (size_t)row * D_MODEL;
  outr[t]       = d0 * rstd * g[t]       + b[t];
  outr[t + 256] = d1 * rstd * g[t + 256] + b[t + 256];
}

__global__ __launch_bounds__(256) void ln_dual_kernel(
    const float* __restrict__ in, const float* __restrict__ g,
    const float* __restrict__ b, float* __restrict__ out,
    unsigned short* __restrict__ out16) {
  int row = blockIdx.x;
  int t = threadIdx.x;
  const float* xr = in + (size_t)row * D_MODEL;
  float v0 = xr[t], v1 = xr[t + 256];
  __shared__ float red[256];
  red[t] = v0 + v1;
  __syncthreads();
  for (int s = 128; s > 0; s >>= 1) { if (t < s) red[t] += red[t + s]; __syncthreads(); }
  float mean = red[0] * (1.0f / 512.0f);
  __syncthreads();
  float d0 = v0 - mean, d1 = v1 - mean;
  red[t] = d0 * d0 + d1 * d1;
  __syncthreads();
  for (int s = 128; s > 0; s >>= 1) { if (t < s) red[t] += red[t + s]; __syncthreads(); }
  float var = red[0] * (1.0f / 512.0f);
  float rstd = 1.0f / sqrtf(var + 1e-5f);
  float* outr = out + (size_t)row * D_MODEL;
  unsigned short* o16 = out16 + (size_t)row * D_MODEL;
  float r0 = d0 * rstd * g[t] + b[t];
  float r1 = d1 * rstd * g[t + 256] + b[t + 256];
  outr[t] = r0;       o16[t] = f2bf(r0);
  outr[t + 256] = r1; o16[t + 256] = f2bf(r1);
}

// MODE 0: +bias   1: gelu(+bias)   2: +bias +R   3: elu((+bias)*scl*g + bb)
__device__ __forceinline__ float epilogue_apply(int MODE, float v, float r,
                                                float g, float bb, float scl) {
  if (MODE == 1) {
    v = 0.5f * v * (1.0f + erff(v * 0.7071067811865475f));
  } else if (MODE == 2) {
    v += r;
  } else if (MODE == 3) {
    v = v * scl * g + bb;
    v = (v > 0.f) ? v : expm1f(v);
  }
  return v;
}

// ================= bf16 MFMA GEMM core (64x64, dbuf — verified R6) ========

__device__ __forceinline__ void gload16(const void* g, void* l) {
  __builtin_amdgcn_global_load_lds(
      (const __attribute__((address_space(1))) unsigned int*)g,
      (__attribute__((address_space(3))) unsigned int*)l, 16, 0, 0);
}

// bijective XCD-chunked swizzle (m204)
__device__ __forceinline__ int xcd_swz(int orig, int nwg) {
  int q = nwg >> 3, r = nwg & 7;
  int x = orig & 7, o = orig >> 3;
  return (x < r ? x * (q + 1) : r * (q + 1) + (x - r) * q) + o;
}

__device__ __forceinline__ void stage64(const unsigned short* __restrict__ G,
                                        int ldk, int row0, int k0,
                                        unsigned short* lds, int tid) {
  const int wave = tid >> 6;
#pragma unroll
  for (int iss = 0; iss < 2; ++iss) {
    int s = iss * 256 + tid;          // 512 slots of 16B
    int r = s >> 3;
    int cs = (s & 7) ^ (r & 7);
    gload16(G + (size_t)(row0 + r) * ldk + k0 + cs * 8,
            lds + (size_t)(iss * 256 + wave * 64) * 8);
  }
}

// swizzled fragment read: row-major [R][64] shorts, 16B chunk ^= row&7
__device__ __forceinline__ short8 frag64(const unsigned short* t, int row,
                                         int chunk) {
  return *(const short8*)(t + row * 64 + ((chunk ^ (row & 7)) * 8));
}

struct Acc4 { floatx4 v[2][2]; };

__device__ __forceinline__ void gemm64_core(
    const unsigned short* __restrict__ A, int lda,
    const unsigned short* __restrict__ Bt, int ldb, int K, int bm, int bn,
    unsigned short* lds /*16384 shorts*/, int tid, Acc4& out) {
  const int wave = tid >> 6, lane = tid & 63;
  const int wm = (wave >> 1) * 32, wn = (wave & 1) * 32;
  const int quad = lane >> 4, l16 = lane & 15;
  floatx4 z = {0.f, 0.f, 0.f, 0.f};
  floatx4 a00 = z, a01 = z, a10 = z, a11 = z;
  stage64(A, lda, bm, 0, lds, tid);
  stage64(Bt, ldb, bn, 0, lds + 4096, tid);
  __syncthreads();
  const int nk = K >> 6;
  for (int t = 0; t < nk; ++t) {
    const int cur = (t & 1) * 8192;
    if (t + 1 < nk) {
      const int nxt = 8192 - cur;
      stage64(A, lda, bm, (t + 1) << 6, lds + nxt, tid);
      stage64(Bt, ldb, bn, (t + 1) << 6, lds + nxt + 4096, tid);
    }
    const unsigned short* At = lds + cur;
    const unsigned short* Bl = lds + cur + 4096;
#pragma unroll
    for (int ks = 0; ks < 2; ++ks) {
      short8 f0 = frag64(At, wm + l16,      ks * 4 + quad);
      short8 f1 = frag64(At, wm + 16 + l16, ks * 4 + quad);
      short8 g0 = frag64(Bl, wn + l16,      ks * 4 + quad);
      short8 g1 = frag64(Bl, wn + 16 + l16, ks * 4 + quad);
      a00 = __builtin_amdgcn_mfma_f32_16x16x32_bf16(f0, g0, a00, 0, 0, 0);
      a01 = __builtin_amdgcn_mfma_f32_16x16x32_bf16(f0, g1, a01, 0, 0, 0);
      a10 = __builtin_amdgcn_mfma_f32_16x16x32_bf16(f1, g0, a10, 0, 0, 0);
      a11 = __builtin_amdgcn_mfma_f32_16x16x32_bf16(f1, g1, a11, 0, 0, 0);
    }
    __syncthreads();
  }
  out.v[0][0] = a00; out.v[0][1] = a01; out.v[1][0] = a10; out.v[1][1] = a11;
}

// OUT bitmask: 1 = fp32 C, 2 = bf16 C16
template <int MODE, int OUT>
__global__ __launch_bounds__(256) void bgemm_kernel(
    const unsigned short* __restrict__ A, const unsigned short* __restrict__ Bt,
    const float* __restrict__ bias, const float* __restrict__ R,
    const float* __restrict__ gvec, const float* __restrict__ bvec,
    float* __restrict__ C, unsigned short* __restrict__ C16,
    int M, int N, int K, float scl) {
  __shared__ unsigned short lds[16384];
  const int tid = threadIdx.x;
  const int gridN = N >> 6;
  const int wgid = xcd_swz(blockIdx.x, (int)gridDim.x);
  const int bn = (wgid % gridN) * 64;
  const int bm = (wgid / gridN) * 64;
  Acc4 acc;
  gemm64_core(A, K, Bt, K, K, bm, bn, lds, tid, acc);
  const int wave = tid >> 6, lane = tid & 63;
  const int wm = (wave >> 1) * 32, wn = (wave & 1) * 32;
  const int quad = lane >> 4, l16 = lane & 15;
#pragma unroll
  for (int i = 0; i < 2; ++i) {
#pragma unroll
    for (int j = 0; j < 2; ++j) {
      int col = bn + wn + j * 16 + l16;
#pragma unroll
      for (int p = 0; p < 4; ++p) {
        int row = bm + wm + i * 16 + quad * 4 + p;
        float v = acc.v[i][j][p] + bias[col];
        v = epilogue_apply(MODE, v, (MODE == 2) ? R[(size_t)row * N + col] : 0.f,
                           (MODE == 3) ? gvec[col] : 0.f,
                           (MODE == 3) ? bvec[col] : 0.f, scl);
        if (OUT & 1) C[(size_t)row * N + col] = v;
        if (OUT & 2) C16[(size_t)row * N + col] = f2bf(v);
      }
    }
  }
}

template <int MODE, int OUT>
static void run_bgemm(const unsigned short* A, const unsigned short* Bt,
                      const float* bias, const float* R, const float* g,
                      const float* bb, float* C, unsigned short* C16,
                      int M, int N, int K, float scl, hipStream_t stream) {
  int nwg = (N / 64) * (M / 64);
  bgemm_kernel<MODE, OUT><<<nwg, 256, 0, stream>>>(A, Bt, bias, R, g, bb, C,
                                                   C16, M, N, K, scl);
}

// fused QKV: one M x 1536 x 512 GEMM over concatenated [Wq;Wk;Wv] rows.
// seg 0 -> Q fp32, seg 1 -> K bf16 ONLY (scores+gathers), seg 2 -> V fp32.
__global__ __launch_bounds__(256) void qkv_gemm_kernel(
    const unsigned short* __restrict__ A, const unsigned short* __restrict__ Bt,
    const float* __restrict__ bqp, const float* __restrict__ bkp,
    const float* __restrict__ bvp, float* __restrict__ Cq,
    float* __restrict__ Cv, unsigned short* __restrict__ K16o, int M, int K) {
  __shared__ unsigned short lds[16384];
  const int tid = threadIdx.x;
  const int gridN = 24;  // 1536/64
  const int wgid = xcd_swz(blockIdx.x, (int)gridDim.x);
  const int bn = (wgid % gridN) * 64;
  const int bm = (wgid / gridN) * 64;
  Acc4 acc;
  gemm64_core(A, K, Bt, K, K, bm, bn, lds, tid, acc);
  const int wave = tid >> 6, lane = tid & 63;
  const int wm = (wave >> 1) * 32, wn = (wave & 1) * 32;
  const int quad = lane >> 4, l16 = lane & 15;
#pragma unroll
  for (int i = 0; i < 2; ++i) {
#pragma unroll
    for (int j = 0; j < 2; ++j) {
      int col = bn + wn + j * 16 + l16;
      int seg = col >> 9, nn = col & 511;  // seg uniform per (block,wave,j)
      const float* bp = (seg == 0) ? bqp : (seg == 1) ? bkp : bvp;
      float bsv = bp[nn];
#pragma unroll
      for (int p = 0; p < 4; ++p) {
        int row = bm + wm + i * 16 + quad * 4 + p;
        float v = acc.v[i][j][p] + bsv;
        if (seg == 1) {
          K16o[(size_t)row * 512 + nn] = f2bf(v);
        } else {
          float* Cd = (seg == 0) ? Cq : Cv;
          Cd[(size_t)row * 512 + nn] = v;
        }
      }
    }
  }
}

// conv GEMM (distill): C = elu((A_shift @ Bt + bias) * scl * g + bb)
// A virtual (M x 1536): A[row][k*512+c] = xln16[b, (l+k-1) mod L, c]
__global__ __launch_bounds__(256) void conv_gemm_kernel(
    const unsigned short* __restrict__ Axl, const unsigned short* __restrict__ Bt,
    const float* __restrict__ bias, const float* __restrict__ gvec,
    const float* __restrict__ bvec, float* __restrict__ C,
    int M, int L, int log2L, float scl) {
  __shared__ unsigned short lds[16384];
  const int tid = threadIdx.x;
  const int wgid = xcd_swz(blockIdx.x, (int)gridDim.x);
  const int bn = (wgid & 7) * 64;   // gridN = 8
  const int bm = (wgid >> 3) * 64;
  const int wave = tid >> 6, lane = tid & 63;
  const int wm = (wave >> 1) * 32, wn = (wave & 1) * 32;
  const int quad = lane >> 4, l16 = lane & 15;
  floatx4 z = {0.f, 0.f, 0.f, 0.f};
  floatx4 a00 = z, a01 = z, a10 = z, a11 = z;

#define STAGE_A_CONV(T, DST)                                               \
  {                                                                        \
    _Pragma("unroll") for (int iss = 0; iss < 2; ++iss) {                  \
      int s = iss * 256 + tid;                                             \
      int r = s >> 3;                                                      \
      int cs = (s & 7) ^ (r & 7);                                          \
      int row = bm + r;                                                    \
      int li = row & (L - 1);                                              \
      int bb2 = row >> log2L;                                              \
      int l2 = (li + ((T) >> 3) - 1 + L) & (L - 1);                        \
      gload16(Axl + (((size_t)((bb2 << log2L) + l2)) << 9) +               \
                  (((T) & 7) << 6) + cs * 8,                               \
              (DST) + (size_t)(iss * 256 + wave * 64) * 8);                \
    }                                                                      \
  }

  STAGE_A_CONV(0, lds);
  stage64(Bt, 1536, bn, 0, lds + 4096, tid);
  __syncthreads();
  for (int t = 0; t < 24; ++t) {
    const int cur = (t & 1) * 8192;
    if (t + 1 < 24) {
      const int nxt = 8192 - cur;
      STAGE_A_CONV(t + 1, lds + nxt);
      stage64(Bt, 1536, bn, (t + 1) << 6, lds + nxt + 4096, tid);
    }
    const unsigned short* At = lds + cur;
    const unsigned short* Bl = lds + cur + 4096;
#pragma unroll
    for (int ks = 0; ks < 2; ++ks) {
      short8 f0 = frag64(At, wm + l16,      ks * 4 + quad);
      short8 f1 = frag64(At, wm + 16 + l16, ks * 4 + quad);
      short8 g0 = frag64(Bl, wn + l16,      ks * 4 + quad);
      short8 g1 = frag64(Bl, wn + 16 + l16, ks * 4 + quad);
      a00 = __builtin_amdgcn_mfma_f32_16x16x32_bf16(f0, g0, a00, 0, 0, 0);
      a01 = __builtin_amdgcn_mfma_f32_16x16x32_bf16(f0, g1, a01, 0, 0, 0);
      a10 = __builtin_amdgcn_mfma_f32_16x16x32_bf16(f1, g0, a10, 0, 0, 0);
      a11 = __builtin_amdgcn_mfma_f32_16x16x32_bf16(f1, g1, a11, 0, 0, 0);
    }
    __syncthreads();
  }
#undef STAGE_A_CONV
  floatx4 accs[2][2] = {{a00, a01}, {a10, a11}};
#pragma unroll
  for (int i = 0; i < 2; ++i) {
#pragma unroll
    for (int j = 0; j < 2; ++j) {
      int col = bn + wn + j * 16 + l16;
      float gv = gvec[col], bbv = bvec[col], bsv = bias[col];
#pragma unroll
      for (int p = 0; p < 4; ++p) {
        int row = bm + wm + i * 16 + quad * 4 + p;
        float v = accs[i][j][p] + bsv;
        v = epilogue_apply(3, v, 0.f, gv, bbv, scl);
        C[(size_t)row * 512 + col] = v;
      }
    }
  }
}

// -------- fused sparse QK sampling: idx (threefry) + gather-dot + M-reduce
// block 0 additionally zeroes vmean (consumed by NEXT dispatch -> no race)
__global__ __launch_bounds__(256) void sparse_qk_fused_kernel(
    const float* __restrict__ Q, const unsigned short* __restrict__ K16,
    float* __restrict__ Mout, float* __restrict__ vmean, int B, int L, int U,
    uint32_t k0, uint32_t k1) {
  __shared__ int idxl[64];
  __shared__ float wmax[4][8];
  __shared__ float wsum[4][8];
  int bl = blockIdx.x;  // b*L + l
  int b = bl / L, l = bl - b * L;
  int tid = threadIdx.x;
  int wave = tid >> 6, lane = tid & 63;
  if (bl == 0) {
    for (int k2 = tid; k2 < 4 * D_MODEL; k2 += 256) vmean[k2] = 0.f;
  }
  if (tid < U) {
    uint32_t o0, o1;
    threefry2x32(k0, k1, 0u, (uint32_t)(l * U + tid), &o0, &o1);
    idxl[tid] = (int)((o0 ^ o1) & (uint32_t)(L - 1));
  }
  int h = lane >> 3;
  const float4* qr = (const float4*)(Q + (size_t)bl * D_MODEL + lane * 8);
  float4 q0 = qr[0], q1 = qr[1];
  float qv[8] = {q0.x, q0.y, q0.z, q0.w, q1.x, q1.y, q1.z, q1.w};
  __syncthreads();
  float mx = -INFINITY, sm = 0.f;
  for (int u = wave; u < U; u += 4) {
    int ki = idxl[u];
    short8 k8 = *(const short8*)(K16 + ((size_t)b * L + ki) * D_MODEL + lane * 8);
    float p = 0.f;
#pragma unroll
    for (int e = 0; e < 8; ++e) p += qv[e] * bf2f((unsigned short)k8[e]);
    p += __shfl_xor(p, 1);
    p += __shfl_xor(p, 2);
    p += __shfl_xor(p, 4);
    mx = fmaxf(mx, p);
    sm += p;
  }
  if ((lane & 7) == 0) { wmax[wave][h] = mx; wsum[wave][h] = sm; }
  __syncthreads();
  if (tid < 8) {
    float m = fmaxf(fmaxf(wmax[0][tid], wmax[1][tid]),
                    fmaxf(wmax[2][tid], wmax[3][tid]));
    float s = wsum[0][tid] + wsum[1][tid] + wsum[2][tid] + wsum[3][tid];
    Mout[((size_t)(b * NH + tid)) * L + l] = m - s / (float)L;
  }
}

// ------- top-k (ballot order-statistics) + vmean partial, merged dispatch --
// blocks [0,32): topk per bh; blocks [32, 32+64*B): vmean partial chunks.
template <int NE>  // NE = L/256 elems per lane
__global__ __launch_bounds__(256) void topk_vmean_kernel(
    const float* __restrict__ Mv, const float* __restrict__ Q,
    const float* __restrict__ V, float* __restrict__ vmean,
    int* __restrict__ Mtop, unsigned short* __restrict__ qred16,
    int u, int L) {
  int blk = blockIdx.x;
  int t = threadIdx.x;
  if (blk >= 32) {
    // vmean partial: 64 chunks x B batches (vmean zeroed in prior dispatch)
    int idx = blk - 32;
    int b2 = idx >> 6, chunk = idx & 63;
    int rows = L >> 6;
    const float* base = V + ((size_t)b2 * L + (size_t)chunk * rows) * D_MODEL;
    float s0 = 0.f, s1 = 0.f;
    for (int r = 0; r < rows; ++r) {
      s0 += base[(size_t)r * D_MODEL + t];
      s1 += base[(size_t)r * D_MODEL + t + 256];
    }
    float invL = 1.0f / (float)L;
    atomicAdd(&vmean[b2 * D_MODEL + t], s0 * invL);
    atomicAdd(&vmean[b2 * D_MODEL + t + 256], s1 * invL);
    return;
  }
  int bh = blk;
  int b = bh >> 3, h = bh & 7;
  int wave = t >> 6, lane = t & 63;
  const int base = wave * 64 * NE;
  const float* src = Mv + (size_t)bh * (NE * 256);
  uint32_t ov[NE];
#pragma unroll
  for (int i = 0; i < NE; ++i) {
    uint32_t bits = __float_as_uint(src[base + i * 64 + lane]);
    uint32_t m = (uint32_t)((int32_t)bits >> 31) | 0x80000000u;
    ov[i] = bits ^ m;
  }
  uint32_t T = 0;
  for (int bit = 31; bit >= 0; --bit) {
    uint32_t cand = T | (1u << bit);
    int c = 0;
#pragma unroll
    for (int i = 0; i < NE; ++i)
      c += (int)__popcll(__ballot(ov[i] >= cand));
    if (c >= u) T = cand;
  }
  int c_gt = 0;
#pragma unroll
  for (int i = 0; i < NE; ++i)
    c_gt += (int)__popcll(__ballot(ov[i] > T));
  int need = u - c_gt;
  int I = 0;
  for (int bit = 10; bit >= 0; --bit) {
    int cand = I | (1 << bit);
    int c = 0;
#pragma unroll
    for (int i = 0; i < NE; ++i)
      c += (int)__popcll(__ballot(ov[i] == T && (base + i * 64 + lane) < cand));
    if (c < need) I = cand;
  }
  __shared__ uint32_t kOrd[160];
  __shared__ int kIdx[160];
  __shared__ int smTop[40];
  int cnt_pre = 0;
#pragma unroll
  for (int i = 0; i < NE; ++i) {
    int ix = base + i * 64 + lane;
    bool sel = (ov[i] > T) || (ov[i] == T && ix <= I);
    unsigned long long bal = __ballot(sel);
    if (sel) {
      int pos = wave * u + cnt_pre +
                (int)__popcll(bal & ((1ull << lane) - 1ull));
      kOrd[pos] = ov[i];
      kIdx[pos] = ix;
    }
    cnt_pre += (int)__popcll(bal);
  }
  __syncthreads();
  int total = 4 * u;
  if (t < total) {
    uint32_t myo = kOrd[t];
    int myi = kIdx[t];
    int rank = 0;
    for (int j = 0; j < total; ++j) {
      uint32_t jo = kOrd[j];
      int ji = kIdx[j];
      rank += (jo > myo || (jo == myo && ji < myi)) ? 1 : 0;
    }
    if (rank < u) {
      Mtop[bh * u + rank] = myi;
      smTop[rank] = myi;
    }
  }
  __syncthreads();
  int d = t & 63;
  for (int r = t >> 6; r < 64; r += 4) {
    float v = 0.f;
    if (r < u) {
      int l = smTop[r];
      v = Q[((size_t)(b * L + l)) * D_MODEL + h * DH + d];
    }
    qred16[((size_t)bh * 64 + r) * 64 + d] = f2bf(v);
  }
}

static void run_topk(const float* Mv, const float* Q, const float* V,
                     float* vmean, int* Mtop, unsigned short* qred16, int L,
                     int u, int B, hipStream_t stream) {
  int nblk = 32 + 64 * B;
  if (L == 2048)
    topk_vmean_kernel<8><<<nblk, 256, 0, stream>>>(Mv, Q, V, vmean, Mtop, qred16, u, L);
  else if (L == 1024)
    topk_vmean_kernel<4><<<nblk, 256, 0, stream>>>(Mv, Q, V, vmean, Mtop, qred16, u, L);
  else
    topk_vmean_kernel<2><<<nblk, 256, 0, stream>>>(Mv, Q, V, vmean, Mtop, qred16, u, L);
}

// ctx fill: pure vmean broadcast as bf16 (selected rows overwritten later
// by attn_pv before O-proj reads them). Vectorized x4.
__global__ __launch_bounds__(256) void fill_ctx_kernel(
    const float* __restrict__ vmean, unsigned short* __restrict__ O16, int B,
    int L) {
  int i4 = (blockIdx.x * 256 + threadIdx.x) * 4;
  int total = B * L * D_MODEL;
  if (i4 >= total) return;
  int dcol = i4 & 511;
  int b = i4 / (D_MODEL * L);
  const float* vm = vmean + b * D_MODEL + dcol;
  ushort4 o;
  o.x = f2bf(vm[0]); o.y = f2bf(vm[1]); o.z = f2bf(vm[2]); o.w = f2bf(vm[3]);
  *(ushort4*)(O16 + i4) = o;
}

// S[z][U][L] = 0.125 * Qred16[z] @ K16_z^T (rows >= U not written)
__global__ __launch_bounds__(256) void scores_mfma_kernel(
    const unsigned short* __restrict__ qred16,
    const unsigned short* __restrict__ k16, float* __restrict__ S, int L,
    int U) {
  __shared__ unsigned short lds[16384];
  const int z = blockIdx.y;
  const int b = z >> 3, h = z & 7;
  const int bn = blockIdx.x * 64;
  const int tid = threadIdx.x;
  Acc4 acc;
  gemm64_core(qred16 + (size_t)z * 4096, 64,
              k16 + (size_t)b * L * D_MODEL + h * DH, D_MODEL, 64, 0, bn, lds,
              tid, acc);
  float* Sz = S + (size_t)z * 64 * L;
  const int wave = tid >> 6, lane = tid & 63;
  const int wm = (wave >> 1) * 32, wn = (wave & 1) * 32;
  const int quad = lane >> 4, l16 = lane & 15;
#pragma unroll
  for (int i = 0; i < 2; ++i) {
#pragma unroll
    for (int j = 0; j < 2; ++j) {
      int col = bn + wn + j * 16 + l16;
#pragma unroll
      for (int p = 0; p < 4; ++p) {
        int row = wm + i * 16 + quad * 4 + p;
        if (row < U) Sz[(size_t)row * L + col] = 0.125f * acc.v[i][j][p];
      }
    }
  }
}

// ---- fused softmax-stats + PV + bf16 write (one block per z, no atomics) --
// Each z owns disjoint (row, 64-col head segment) outputs -> race-free.
#define PV_LC 128

template <int U>
__global__ __launch_bounds__(256) void attn_pv_kernel(
    const float* __restrict__ S, const float* __restrict__ V,
    const int* __restrict__ Mtop, unsigned short* __restrict__ O16, int L) {
  __shared__ float Pl[U][PV_LC];
  __shared__ float Vl[PV_LC][DH + 4];
  __shared__ float Msh[U], Ish[U];
  const int z = blockIdx.x;
  const int b = z >> 3, h = z & 7;
  const int tid = threadIdx.x;
  const int wave = tid >> 6, lane = tid & 63;
  constexpr int NJ = (U + 3) / 4;
  const float* Sz = S + (size_t)z * 64 * L;
  // phase A: per-row max and inverse exp-sum (rows r = wave + 4j)
  for (int j = 0; j < NJ; ++j) {
    int r = wave + 4 * j;
    if (r >= U) continue;
    const float* row = Sz + (size_t)r * L;
    float m = -INFINITY;
    for (int c = lane; c < L; c += 64) m = fmaxf(m, row[c]);
#pragma unroll
    for (int k = 32; k; k >>= 1) m = fmaxf(m, __shfl_xor(m, k));
    float s = 0.f;
    for (int c = lane; c < L; c += 64) s += expf(row[c] - m);
#pragma unroll
    for (int k = 32; k; k >>= 1) s += __shfl_xor(s, k);
    if (lane == 0) { Msh[r] = m; Ish[r] = 1.0f / s; }
  }
  __syncthreads();
  // phase B: serial-chunk PV with P staged (exp applied at stage)
  float acc[NJ] = {};
  for (int c0 = 0; c0 < L; c0 += PV_LC) {
    for (int i4 = tid; i4 < U * (PV_LC / 4); i4 += 256) {
      int r = i4 / (PV_LC / 4);
      int lq = (i4 % (PV_LC / 4)) * 4;
      float4 p4 = *(const float4*)(Sz + (size_t)r * L + c0 + lq);
      float mr = Msh[r], ir = Ish[r];
      Pl[r][lq + 0] = expf(p4.x - mr) * ir;
      Pl[r][lq + 1] = expf(p4.y - mr) * ir;
      Pl[r][lq + 2] = expf(p4.z - mr) * ir;
      Pl[r][lq + 3] = expf(p4.w - mr) * ir;
    }
    const float* Vb = V + ((size_t)b * L + c0) * D_MODEL + h * DH;
    for (int i4 = tid; i4 < PV_LC * (DH / 4); i4 += 256) {
      int l = i4 >> 4;
      int d4 = (i4 & 15) * 4;
      float4 v4 = *(const float4*)(Vb + (size_t)l * D_MODEL + d4);
      Vl[l][d4 + 0] = v4.x; Vl[l][d4 + 1] = v4.y;
      Vl[l][d4 + 2] = v4.z; Vl[l][d4 + 3] = v4.w;
    }
    __syncthreads();
    for (int l = 0; l < PV_LC; ++l) {
      float vv = Vl[l][lane];
#pragma unroll
      for (int j = 0; j < NJ; ++j) {
        int r = wave + 4 * j;
        if (r < U) acc[j] += Pl[r][l] * vv;
      }
    }
    __syncthreads();
  }
  // write selected rows directly as bf16 (overwrites fill_ctx placeholder)
#pragma unroll
  for (int j = 0; j < NJ; ++j) {
    int r = wave + 4 * j;
    if (r < U) {
      int ml = Mtop[z * U + r];
      O16[((size_t)(b * L + ml)) * D_MODEL + h * DH + lane] = f2bf(acc[j]);
    }
  }
}

static void run_attn_pv(const float* S, const float* V, const int* Mtop,
                        unsigned short* O16, int L, int U,
                        hipStream_t stream) {
  if (U == 40)      attn_pv_kernel<40><<<32, 256, 0, stream>>>(S, V, Mtop, O16, L);
  else if (U == 35) attn_pv_kernel<35><<<32, 256, 0, stream>>>(S, V, Mtop, O16, L);
  else              attn_pv_kernel<64><<<32, 256, 0, stream>>>(S, V, Mtop, O16, L);
}

// ---------------- maxpool k=3 s=2, dual fp32/bf16 out ---------------------
__global__ void maxpool_kernel(const float* __restrict__ Y,
                               float* __restrict__ X,
                               unsigned short* __restrict__ Xb, int B, int L) {
  int Lo = L / 2;
  int i = blockIdx.x * 256 + threadIdx.x;
  int total = B * Lo * D_MODEL;
  if (i >= total) return;
  int d = i % D_MODEL;
  int lp = (i / D_MODEL) % Lo;
  int b = i / (D_MODEL * Lo);
  int l0 = 2 * lp - 1;
  float m = -INFINITY;
#pragma unroll
  for (int k = 0; k < 3; ++k) {
    int l = l0 + k;
    if (l >= 0 && l < L) m = fmaxf(m, Y[((size_t)(b * L + l)) * D_MODEL + d]);
  }
  X[i] = m;
  Xb[i] = f2bf(m);
}

// ==========================================================================
extern "C" void kernel_launch(void* const* d_in, const int* in_sizes, int n_in,
                              void* d_out, int out_size, void* d_ws,
                              size_t ws_size, hipStream_t stream) {
  const float* x_enc  = (const float*)d_in[0];
  const float* emb_w  = (const float*)d_in[1];
  const float* Wq     = (const float*)d_in[2];
  const float* bq     = (const float*)d_in[3];
  const float* Wk     = (const float*)d_in[4];
  const float* bk     = (const float*)d_in[5];
  const float* Wv     = (const float*)d_in[6];
  const float* bv     = (const float*)d_in[7];
  const float* Wo     = (const float*)d_in[8];
  const float* bo     = (const float*)d_in[9];
  const float* ln1_g  = (const float*)d_in[10];
  const float* ln1_b  = (const float*)d_in[11];
  const float* ff_w1  = (const float*)d_in[12];
  const float* ff_b1  = (const float*)d_in[13];
  const float* ff_w2  = (const float*)d_in[14];
  const float* ff_b2  = (const float*)d_in[15];
  const float* ln2_g  = (const float*)d_in[16];
  const float* ln2_b  = (const float*)d_in[17];
  const float* cv_w   = (const float*)d_in[18];
  const float* cv_b   = (const float*)d_in[19];
  const float* bn_g   = (const float*)d_in[20];
  const float* bn_b   = (const float*)d_in[21];
  const float* norm_g = (const float*)d_in[22];
  const float* norm_b = (const float*)d_in[23];

  const int B = 4, L0 = 2048, EL = 3;
  const size_t SZ = (size_t)B * 2048 * 512;
  float* ws   = (float*)d_ws;
  float* xbuf = ws;
  float* ebuf = ws + SZ;   // layer0 xb16; pre-LN temp; Sbuf
  float* qbuf = ws + 2 * SZ;
  float* kbuf = ws + 3 * SZ;   // hosts k16 (bf16 K) per layer
  float* vbuf = ws + 4 * SZ;
  float* obuf = ws + 5 * SZ;   // unused fp32 ctx (kept for layout stability)
  float* sm   = ws + 6 * SZ;
  // scratch region:
  float*         d_M     = sm;                          // 65536
  int*           d_Mtop  = (int*)(sm + 65536);          // 1280
  float*         d_vmean = sm + 65536 + 1280;           // 2048
  unsigned short* qred16 = (unsigned short*)(sm + 65536 + 1280 + 2048 + 2048);
  // pre-cast bf16 weights region at ws + 6SZ + 160000 floats
  unsigned short* wgt  = (unsigned short*)(ws + 6 * SZ + 160000);
  unsigned short* qkvw = wgt;                    // EL x [Wq;Wk;Wv] (786432 ea)
  unsigned short* wof  = wgt + 3 * 786432;       // [wow | w1w | w2w]
  unsigned short* wow  = wof;
  unsigned short* w1w  = wof + 786432;
  unsigned short* w2w  = wof + 2 * 786432;
  unsigned short* cvw2 = wof + 3 * 786432;       // 2 x 786432 (k*512+c order)

  float* Sbuf = ebuf;
  const float inv_s = 1.0f / sqrtf(1.0f + 1e-5f);
  (void)obuf;

  // ---- upfront weight casts: 3 dispatches ----
  cast3_qkv_kernel<<<3 * 768, 256, 0, stream>>>(Wq, Wk, Wv, qkvw);
  cast3_flat_kernel<<<3 * 768, 256, 0, stream>>>(Wo, ff_w1, ff_w2, wof);
  cast_cvperm_kernel<<<6144, 256, 0, stream>>>(cv_w, cvw2);

  // layer-0 x bf16 fused into embed (-> ebuf)
  embed_kernel<<<ceil_div(B * L0 * D_MODEL, 256), 256, 0, stream>>>(
      x_enc, emb_w, xbuf, (unsigned short*)ebuf, B, L0);
  unsigned short* xb16 = (unsigned short*)ebuf;  // current layer's bf16 x

  int L = L0;
  int log2L = 11;
  for (int i = 0; i < EL; ++i) {
    const int M_ = B * L;
    int c = 5 * (int)ceil(log((double)L));
    int U = c < L ? c : L;
    unsigned short* k16 = (unsigned short*)kbuf;

    // QKV fused GEMM (64^2 tile, N=1536)
    qkv_gemm_kernel<<<24 * (M_ / 64), 256, 0, stream>>>(
        xb16, qkvw + (size_t)i * 786432, bq + i * 512, bk + i * 512,
        bv + i * 512, qbuf, vbuf, k16, M_, 512);

    uint32_t lk0, lk1, k20, k21;
    threefry2x32(0u, 42u, 0u, (uint32_t)i, &lk0, &lk1);
    threefry2x32(lk0, lk1, 0u, 1u, &k20, &k21);

    // fused idx + gather-dot + M reduce (+vmean zero in block 0)
    sparse_qk_fused_kernel<<<B * L, 256, 0, stream>>>(qbuf, k16, d_M, d_vmean,
                                                      B, L, U, k20, k21);
    // topk + qred gather + vmean partial (merged dispatch)
    run_topk(d_M, qbuf, vbuf, d_vmean, d_Mtop, qred16, L, U, B, stream);
    // ctx bf16 broadcast -> qbuf shorts (Q dead after topk's gather)
    unsigned short* ab16 = (unsigned short*)qbuf;
    fill_ctx_kernel<<<ceil_div(B * L * D_MODEL / 4, 256), 256, 0, stream>>>(
        d_vmean, ab16, B, L);

    scores_mfma_kernel<<<dim3(L / 64, B * NH), 256, 0, stream>>>(qred16, k16,
                                                                 Sbuf, L, U);
    // fused stats + PV + direct bf16 write of selected rows
    run_attn_pv(Sbuf, vbuf, d_Mtop, ab16, L, U, stream);

    // O-proj (+residual) -> ebuf fp32
    run_bgemm<2, 1>(ab16, wow + (size_t)i * 262144, bo + i * 512, xbuf,
                    nullptr, nullptr, ebuf, nullptr, M_, 512, 512, 0.f,
                    stream);
    // ln1 dual-writes x fp32 + bf16 (FF1 A input) -> qbuf shorts
    ln_dual_kernel<<<M_, 256, 0, stream>>>(ebuf, ln1_g + i * 512,
                                           ln1_b + i * 512, xbuf, ab16);

    // FF1: bf16-only output -> obuf shorts
    unsigned short* ff1b16 = (unsigned short*)obuf;
    run_bgemm<1, 2>(ab16, w1w + (size_t)i * 262144, ff_b1 + i * 512, nullptr,
                    nullptr, nullptr, nullptr, ff1b16, M_, 512, 512, 0.f,
                    stream);
    // FF2 (+residual) -> ebuf fp32
    run_bgemm<2, 1>(ff1b16, w2w + (size_t)i * 262144, ff_b2 + i * 512, xbuf,
                    nullptr, nullptr, ebuf, nullptr, M_, 512, 512, 0.f,
                    stream);

    if (i < EL - 1) {
      // ln2 dual: fp32 -> xbuf, bf16 -> qbuf (conv GEMM A)
      unsigned short* xln16 = (unsigned short*)qbuf;
      ln_dual_kernel<<<M_, 256, 0, stream>>>(ebuf, ln2_g + i * 512,
                                             ln2_b + i * 512, xbuf, xln16);
      // conv distill as shifted-K GEMM
      conv_gemm_kernel<<<8 * (M_ / 64), 256, 0, stream>>>(
          xln16, cvw2 + (size_t)i * 786432, cv_b + i * 512, bn_g + i * 512,
          bn_b + i * 512, ebuf, M_, L, log2L, inv_s);
      // maxpool dual-writes next-layer x fp32 + bf16 @ vbuf tail
      xb16 = (unsigned short*)vbuf + 6291456;  // byte offset 12.6MB
      maxpool_kernel<<<ceil_div(B * (L / 2) * D_MODEL, 256), 256, 0, stream>>>(
          ebuf, xbuf, xb16, B, L);
      L /= 2;
      log2L -= 1;
    } else {
      ln_kernel<<<M_, 256, 0, stream>>>(ebuf, ln2_g + i * 512,
                                        ln2_b + i * 512, xbuf);
    }
  }

  ln_kernel<<<B * L, 256, 0, stream>>>(xbuf, norm_g, norm_b, (float*)d_out);
}

// Round 11
// 678.363 us; speedup vs baseline: 2.0728x; 2.0728x over previous
//
#include <hip/hip_runtime.h>
#include <cmath>
#include <cstdint>

#define D_MODEL 512
#define NH 8
#define DH 64

static inline int ceil_div(int a, int b) { return (a + b - 1) / b; }

typedef __attribute__((ext_vector_type(8))) short short8;
typedef __attribute__((ext_vector_type(4))) float floatx4;

// fp32 -> bf16 (RNE)
__device__ __forceinline__ unsigned short f2bf(float f) {
  uint32_t u = __float_as_uint(f);
  uint32_t r = (u + 0x7fffu + ((u >> 16) & 1u)) >> 16;
  return (unsigned short)r;
}
__device__ __forceinline__ float bf2f(unsigned short s) {
  return __uint_as_float(((uint32_t)s) << 16);
}

// ---------------- threefry2x32 (JAX-exact) ----------------
#define TF_ROTL(x, r) (((x) << (r)) | ((x) >> (32 - (r))))

__host__ __device__ inline void threefry2x32(uint32_t k0, uint32_t k1,
                                             uint32_t x0, uint32_t x1,
                                             uint32_t* o0, uint32_t* o1) {
  uint32_t ks2 = k0 ^ k1 ^ 0x1BD11BDAu;
  x0 += k0; x1 += k1;
#define TF_R4(a, b, c, d)                                    \
  x0 += x1; x1 = TF_ROTL(x1, a); x1 ^= x0;                   \
  x0 += x1; x1 = TF_ROTL(x1, b); x1 ^= x0;                   \
  x0 += x1; x1 = TF_ROTL(x1, c); x1 ^= x0;                   \
  x0 += x1; x1 = TF_ROTL(x1, d); x1 ^= x0;
  TF_R4(13, 15, 26, 6);  x0 += k1;  x1 += ks2 + 1u;
  TF_R4(17, 29, 16, 24); x0 += ks2; x1 += k0 + 2u;
  TF_R4(13, 15, 26, 6);  x0 += k0;  x1 += k1 + 3u;
  TF_R4(17, 29, 16, 24); x0 += k1;  x1 += ks2 + 4u;
  TF_R4(13, 15, 26, 6);  x0 += ks2; x1 += k0 + 5u;
#undef TF_R4
  *o0 = x0; *o1 = x1;
}

// ---------------- upfront weight casts (multi-source, batched) -------------
__global__ __launch_bounds__(256) void cast3_qkv_kernel(
    const float* __restrict__ s0, const float* __restrict__ s1,
    const float* __restrict__ s2, unsigned short* __restrict__ dst) {
  int sel = blockIdx.x / 768, bb = blockIdx.x % 768;
  int i = (bb * 256 + threadIdx.x) * 4;  // < 786432
  const float* s = (sel == 0) ? s0 : (sel == 1) ? s1 : s2;
  float4 v = *(const float4*)(s + i);
  ushort4 o;
  o.x = f2bf(v.x); o.y = f2bf(v.y); o.z = f2bf(v.z); o.w = f2bf(v.w);
  int layer = i >> 18, off = i & 262143;
  *(ushort4*)(dst + (size_t)layer * 786432 + sel * 262144 + off) = o;
}

__global__ __launch_bounds__(256) void cast3_flat_kernel(
    const float* __restrict__ s0, const float* __restrict__ s1,
    const float* __restrict__ s2, unsigned short* __restrict__ dst) {
  int sel = blockIdx.x / 768, bb = blockIdx.x % 768;
  int i = (bb * 256 + threadIdx.x) * 4;
  const float* s = (sel == 0) ? s0 : (sel == 1) ? s1 : s2;
  float4 v = *(const float4*)(s + i);
  ushort4 o;
  o.x = f2bf(v.x); o.y = f2bf(v.y); o.z = f2bf(v.z); o.w = f2bf(v.w);
  *(ushort4*)(dst + (size_t)sel * 786432 + i) = o;
}

// conv weights permute-cast: w[m][n][c][k] -> dst[m][n][k*512 + c]
__global__ __launch_bounds__(256) void cast_cvperm_kernel(
    const float* __restrict__ src, unsigned short* __restrict__ dst) {
  int o = blockIdx.x * 256 + threadIdx.x;  // < 2*786432
  int m = o / 786432, rem = o % 786432;
  int n = rem / 1536, q = rem % 1536;
  int k = q >> 9, c = q & 511;
  dst[o] = f2bf(src[(size_t)m * 786432 + n * 1536 + c * 3 + k]);
}

// ---------------- embedding + pos encoding, dual fp32/bf16 out ------------
__global__ __launch_bounds__(256) void embed_kernel(
    const float* __restrict__ x_enc, const float* __restrict__ emb_w,
    float* __restrict__ x, unsigned short* __restrict__ xb, int B, int L) {
  int i = blockIdx.x * 256 + threadIdx.x;
  int total = B * L * D_MODEL;
  if (i >= total) return;
  int d = i % D_MODEL;
  int l = (i / D_MODEL) % L;
  int b = i / (D_MODEL * L);
  int lm = (l == 0) ? (L - 1) : (l - 1);
  int lp = (l == L - 1) ? 0 : (l + 1);
  const float* w = emb_w + d * 6;
  const float* xb_in = x_enc + (size_t)b * L * 2;
  float acc = 0.f;
  acc += xb_in[lm * 2 + 0] * w[0] + xb_in[l * 2 + 0] * w[1] + xb_in[lp * 2 + 0] * w[2];
  acc += xb_in[lm * 2 + 1] * w[3] + xb_in[l * 2 + 1] * w[4] + xb_in[lp * 2 + 1] * w[5];
  int j = d >> 1;
  const float coef = -0.017988946039015985f;  // -ln(10000)/512
  float div = expf((float)(2 * j) * coef);
  float ang = (float)l * div;
  float pe = (d & 1) ? cosf(ang) : sinf(ang);
  float v = acc + pe;
  x[i] = v;
  xb[i] = f2bf(v);
}

// ---------------- layer norm over D=512 (plain + dual-output) -------------
__global__ __launch_bounds__(256) void ln_kernel(
    const float* __restrict__ in, const float* __restrict__ g,
    const float* __restrict__ b, float* __restrict__ out) {
  int row = blockIdx.x;
  int t = threadIdx.x;
  const float* xr = in + (size_t)row * D_MODEL;
  float v0 = xr[t], v1 = xr[t + 256];
  __shared__ float red[256];
  red[t] = v0 + v1;
  __syncthreads();
  for (int s = 128; s > 0; s >>= 1) { if (t < s) red[t] += red[t + s]; __syncthreads(); }
  float mean = red[0] * (1.0f / 512.0f);
  __syncthreads();
  float d0 = v0 - mean, d1 = v1 - mean;
  red[t] = d0 * d0 + d1 * d1;
  __syncthreads();
  for (int s = 128; s > 0; s >>= 1) { if (t < s) red[t] += red[t + s]; __syncthreads(); }
  float var = red[0] * (1.0f / 512.0f);
  float rstd = 1.0f / sqrtf(var + 1e-5f);
  float* outr = out + (size_t)row * D_MODEL;
  outr[t]       = d0 * rstd * g[t]       + b[t];
  outr[t + 256] = d1 * rstd * g[t + 256] + b[t + 256];
}

__global__ __launch_bounds__(256) void ln_dual_kernel(
    const float* __restrict__ in, const float* __restrict__ g,
    const float* __restrict__ b, float* __restrict__ out,
    unsigned short* __restrict__ out16) {
  int row = blockIdx.x;
  int t = threadIdx.x;
  const float* xr = in + (size_t)row * D_MODEL;
  float v0 = xr[t], v1 = xr[t + 256];
  __shared__ float red[256];
  red[t] = v0 + v1;
  __syncthreads();
  for (int s = 128; s > 0; s >>= 1) { if (t < s) red[t] += red[t + s]; __syncthreads(); }
  float mean = red[0] * (1.0f / 512.0f);
  __syncthreads();
  float d0 = v0 - mean, d1 = v1 - mean;
  red[t] = d0 * d0 + d1 * d1;
  __syncthreads();
  for (int s = 128; s > 0; s >>= 1) { if (t < s) red[t] += red[t + s]; __syncthreads(); }
  float var = red[0] * (1.0f / 512.0f);
  float rstd = 1.0f / sqrtf(var + 1e-5f);
  float* outr = out + (size_t)row * D_MODEL;
  unsigned short* o16 = out16 + (size_t)row * D_MODEL;
  float r0 = d0 * rstd * g[t] + b[t];
  float r1 = d1 * rstd * g[t + 256] + b[t + 256];
  outr[t] = r0;       o16[t] = f2bf(r0);
  outr[t + 256] = r1; o16[t + 256] = f2bf(r1);
}

// MODE 0: +bias   1: gelu(+bias)   2: +bias +R   3: elu((+bias)*scl*g + bb)
__device__ __forceinline__ float epilogue_apply(int MODE, float v, float r,
                                                float g, float bb, float scl) {
  if (MODE == 1) {
    v = 0.5f * v * (1.0f + erff(v * 0.7071067811865475f));
  } else if (MODE == 2) {
    v += r;
  } else if (MODE == 3) {
    v = v * scl * g + bb;
    v = (v > 0.f) ? v : expm1f(v);
  }
  return v;
}

// ================= bf16 MFMA GEMM core (64x64, dbuf — verified R6) ========

__device__ __forceinline__ void gload16(const void* g, void* l) {
  __builtin_amdgcn_global_load_lds(
      (const __attribute__((address_space(1))) unsigned int*)g,
      (__attribute__((address_space(3))) unsigned int*)l, 16, 0, 0);
}

// bijective XCD-chunked swizzle (m204)
__device__ __forceinline__ int xcd_swz(int orig, int nwg) {
  int q = nwg >> 3, r = nwg & 7;
  int x = orig & 7, o = orig >> 3;
  return (x < r ? x * (q + 1) : r * (q + 1) + (x - r) * q) + o;
}

__device__ __forceinline__ void stage64(const unsigned short* __restrict__ G,
                                        int ldk, int row0, int k0,
                                        unsigned short* lds, int tid) {
  const int wave = tid >> 6;
#pragma unroll
  for (int iss = 0; iss < 2; ++iss) {
    int s = iss * 256 + tid;          // 512 slots of 16B
    int r = s >> 3;
    int cs = (s & 7) ^ (r & 7);
    gload16(G + (size_t)(row0 + r) * ldk + k0 + cs * 8,
            lds + (size_t)(iss * 256 + wave * 64) * 8);
  }
}

// swizzled fragment read: row-major [R][64] shorts, 16B chunk ^= row&7
__device__ __forceinline__ short8 frag64(const unsigned short* t, int row,
                                         int chunk) {
  return *(const short8*)(t + row * 64 + ((chunk ^ (row & 7)) * 8));
}

struct Acc4 { floatx4 v[2][2]; };

__device__ __forceinline__ void gemm64_core(
    const unsigned short* __restrict__ A, int lda,
    const unsigned short* __restrict__ Bt, int ldb, int K, int bm, int bn,
    unsigned short* lds /*16384 shorts*/, int tid, Acc4& out) {
  const int wave = tid >> 6, lane = tid & 63;
  const int wm = (wave >> 1) * 32, wn = (wave & 1) * 32;
  const int quad = lane >> 4, l16 = lane & 15;
  floatx4 z = {0.f, 0.f, 0.f, 0.f};
  floatx4 a00 = z, a01 = z, a10 = z, a11 = z;
  stage64(A, lda, bm, 0, lds, tid);
  stage64(Bt, ldb, bn, 0, lds + 4096, tid);
  __syncthreads();
  const int nk = K >> 6;
  for (int t = 0; t < nk; ++t) {
    const int cur = (t & 1) * 8192;
    if (t + 1 < nk) {
      const int nxt = 8192 - cur;
      stage64(A, lda, bm, (t + 1) << 6, lds + nxt, tid);
      stage64(Bt, ldb, bn, (t + 1) << 6, lds + nxt + 4096, tid);
    }
    const unsigned short* At = lds + cur;
    const unsigned short* Bl = lds + cur + 4096;
#pragma unroll
    for (int ks = 0; ks < 2; ++ks) {
      short8 f0 = frag64(At, wm + l16,      ks * 4 + quad);
      short8 f1 = frag64(At, wm + 16 + l16, ks * 4 + quad);
      short8 g0 = frag64(Bl, wn + l16,      ks * 4 + quad);
      short8 g1 = frag64(Bl, wn + 16 + l16, ks * 4 + quad);
      a00 = __builtin_amdgcn_mfma_f32_16x16x32_bf16(f0, g0, a00, 0, 0, 0);
      a01 = __builtin_amdgcn_mfma_f32_16x16x32_bf16(f0, g1, a01, 0, 0, 0);
      a10 = __builtin_amdgcn_mfma_f32_16x16x32_bf16(f1, g0, a10, 0, 0, 0);
      a11 = __builtin_amdgcn_mfma_f32_16x16x32_bf16(f1, g1, a11, 0, 0, 0);
    }
    __syncthreads();
  }
  out.v[0][0] = a00; out.v[0][1] = a01; out.v[1][0] = a10; out.v[1][1] = a11;
}

// OUT bitmask: 1 = fp32 C, 2 = bf16 C16
template <int MODE, int OUT>
__global__ __launch_bounds__(256) void bgemm_kernel(
    const unsigned short* __restrict__ A, const unsigned short* __restrict__ Bt,
    const float* __restrict__ bias, const float* __restrict__ R,
    const float* __restrict__ gvec, const float* __restrict__ bvec,
    float* __restrict__ C, unsigned short* __restrict__ C16,
    int M, int N, int K, float scl) {
  __shared__ unsigned short lds[16384];
  const int tid = threadIdx.x;
  const int gridN = N >> 6;
  const int wgid = xcd_swz(blockIdx.x, (int)gridDim.x);
  const int bn = (wgid % gridN) * 64;
  const int bm = (wgid / gridN) * 64;
  Acc4 acc;
  gemm64_core(A, K, Bt, K, K, bm, bn, lds, tid, acc);
  const int wave = tid >> 6, lane = tid & 63;
  const int wm = (wave >> 1) * 32, wn = (wave & 1) * 32;
  const int quad = lane >> 4, l16 = lane & 15;
#pragma unroll
  for (int i = 0; i < 2; ++i) {
#pragma unroll
    for (int j = 0; j < 2; ++j) {
      int col = bn + wn + j * 16 + l16;
#pragma unroll
      for (int p = 0; p < 4; ++p) {
        int row = bm + wm + i * 16 + quad * 4 + p;
        float v = acc.v[i][j][p] + bias[col];
        v = epilogue_apply(MODE, v, (MODE == 2) ? R[(size_t)row * N + col] : 0.f,
                           (MODE == 3) ? gvec[col] : 0.f,
                           (MODE == 3) ? bvec[col] : 0.f, scl);
        if (OUT & 1) C[(size_t)row * N + col] = v;
        if (OUT & 2) C16[(size_t)row * N + col] = f2bf(v);
      }
    }
  }
}

template <int MODE, int OUT>
static void run_bgemm(const unsigned short* A, const unsigned short* Bt,
                      const float* bias, const float* R, const float* g,
                      const float* bb, float* C, unsigned short* C16,
                      int M, int N, int K, float scl, hipStream_t stream) {
  int nwg = (N / 64) * (M / 64);
  bgemm_kernel<MODE, OUT><<<nwg, 256, 0, stream>>>(A, Bt, bias, R, g, bb, C,
                                                   C16, M, N, K, scl);
}

// fused QKV: one M x 1536 x 512 GEMM over concatenated [Wq;Wk;Wv] rows.
// seg 0 -> Q fp32, seg 1 -> K bf16 ONLY (scores+gathers), seg 2 -> V fp32.
__global__ __launch_bounds__(256) void qkv_gemm_kernel(
    const unsigned short* __restrict__ A, const unsigned short* __restrict__ Bt,
    const float* __restrict__ bqp, const float* __restrict__ bkp,
    const float* __restrict__ bvp, float* __restrict__ Cq,
    float* __restrict__ Cv, unsigned short* __restrict__ K16o, int M, int K) {
  __shared__ unsigned short lds[16384];
  const int tid = threadIdx.x;
  const int gridN = 24;  // 1536/64
  const int wgid = xcd_swz(blockIdx.x, (int)gridDim.x);
  const int bn = (wgid % gridN) * 64;
  const int bm = (wgid / gridN) * 64;
  Acc4 acc;
  gemm64_core(A, K, Bt, K, K, bm, bn, lds, tid, acc);
  const int wave = tid >> 6, lane = tid & 63;
  const int wm = (wave >> 1) * 32, wn = (wave & 1) * 32;
  const int quad = lane >> 4, l16 = lane & 15;
#pragma unroll
  for (int i = 0; i < 2; ++i) {
#pragma unroll
    for (int j = 0; j < 2; ++j) {
      int col = bn + wn + j * 16 + l16;
      int seg = col >> 9, nn = col & 511;  // seg uniform per (block,wave,j)
      const float* bp = (seg == 0) ? bqp : (seg == 1) ? bkp : bvp;
      float bsv = bp[nn];
#pragma unroll
      for (int p = 0; p < 4; ++p) {
        int row = bm + wm + i * 16 + quad * 4 + p;
        float v = acc.v[i][j][p] + bsv;
        if (seg == 1) {
          K16o[(size_t)row * 512 + nn] = f2bf(v);
        } else {
          float* Cd = (seg == 0) ? Cq : Cv;
          Cd[(size_t)row * 512 + nn] = v;
        }
      }
    }
  }
}

// conv GEMM (distill): C = elu((A_shift @ Bt + bias) * scl * g + bb)
// A virtual (M x 1536): A[row][k*512+c] = xln16[b, (l+k-1) mod L, c]
__global__ __launch_bounds__(256) void conv_gemm_kernel(
    const unsigned short* __restrict__ Axl, const unsigned short* __restrict__ Bt,
    const float* __restrict__ bias, const float* __restrict__ gvec,
    const float* __restrict__ bvec, float* __restrict__ C,
    int M, int L, int log2L, float scl) {
  __shared__ unsigned short lds[16384];
  const int tid = threadIdx.x;
  const int wgid = xcd_swz(blockIdx.x, (int)gridDim.x);
  const int bn = (wgid & 7) * 64;   // gridN = 8
  const int bm = (wgid >> 3) * 64;
  const int wave = tid >> 6, lane = tid & 63;
  const int wm = (wave >> 1) * 32, wn = (wave & 1) * 32;
  const int quad = lane >> 4, l16 = lane & 15;
  floatx4 z = {0.f, 0.f, 0.f, 0.f};
  floatx4 a00 = z, a01 = z, a10 = z, a11 = z;

#define STAGE_A_CONV(T, DST)                                               \
  {                                                                        \
    _Pragma("unroll") for (int iss = 0; iss < 2; ++iss) {                  \
      int s = iss * 256 + tid;                                             \
      int r = s >> 3;                                                      \
      int cs = (s & 7) ^ (r & 7);                                          \
      int row = bm + r;                                                    \
      int li = row & (L - 1);                                              \
      int bb2 = row >> log2L;                                              \
      int l2 = (li + ((T) >> 3) - 1 + L) & (L - 1);                        \
      gload16(Axl + (((size_t)((bb2 << log2L) + l2)) << 9) +               \
                  (((T) & 7) << 6) + cs * 8,                               \
              (DST) + (size_t)(iss * 256 + wave * 64) * 8);                \
    }                                                                      \
  }

  STAGE_A_CONV(0, lds);
  stage64(Bt, 1536, bn, 0, lds + 4096, tid);
  __syncthreads();
  for (int t = 0; t < 24; ++t) {
    const int cur = (t & 1) * 8192;
    if (t + 1 < 24) {
      const int nxt = 8192 - cur;
      STAGE_A_CONV(t + 1, lds + nxt);
      stage64(Bt, 1536, bn, (t + 1) << 6, lds + nxt + 4096, tid);
    }
    const unsigned short* At = lds + cur;
    const unsigned short* Bl = lds + cur + 4096;
#pragma unroll
    for (int ks = 0; ks < 2; ++ks) {
      short8 f0 = frag64(At, wm + l16,      ks * 4 + quad);
      short8 f1 = frag64(At, wm + 16 + l16, ks * 4 + quad);
      short8 g0 = frag64(Bl, wn + l16,      ks * 4 + quad);
      short8 g1 = frag64(Bl, wn + 16 + l16, ks * 4 + quad);
      a00 = __builtin_amdgcn_mfma_f32_16x16x32_bf16(f0, g0, a00, 0, 0, 0);
      a01 = __builtin_amdgcn_mfma_f32_16x16x32_bf16(f0, g1, a01, 0, 0, 0);
      a10 = __builtin_amdgcn_mfma_f32_16x16x32_bf16(f1, g0, a10, 0, 0, 0);
      a11 = __builtin_amdgcn_mfma_f32_16x16x32_bf16(f1, g1, a11, 0, 0, 0);
    }
    __syncthreads();
  }
#undef STAGE_A_CONV
  floatx4 accs[2][2] = {{a00, a01}, {a10, a11}};
#pragma unroll
  for (int i = 0; i < 2; ++i) {
#pragma unroll
    for (int j = 0; j < 2; ++j) {
      int col = bn + wn + j * 16 + l16;
      float gv = gvec[col], bbv = bvec[col], bsv = bias[col];
#pragma unroll
      for (int p = 0; p < 4; ++p) {
        int row = bm + wm + i * 16 + quad * 4 + p;
        float v = accs[i][j][p] + bsv;
        v = epilogue_apply(3, v, 0.f, gv, bbv, scl);
        C[(size_t)row * 512 + col] = v;
      }
    }
  }
}

// -------- fused sparse QK sampling: idx (threefry) + gather-dot + M-reduce
// block 0 additionally zeroes vmean (consumed by NEXT dispatch -> no race)
__global__ __launch_bounds__(256) void sparse_qk_fused_kernel(
    const float* __restrict__ Q, const unsigned short* __restrict__ K16,
    float* __restrict__ Mout, float* __restrict__ vmean, int B, int L, int U,
    uint32_t k0, uint32_t k1) {
  __shared__ int idxl[64];
  __shared__ float wmax[4][8];
  __shared__ float wsum[4][8];
  int bl = blockIdx.x;  // b*L + l
  int b = bl / L, l = bl - b * L;
  int tid = threadIdx.x;
  int wave = tid >> 6, lane = tid & 63;
  if (bl == 0) {
    for (int k2 = tid; k2 < 4 * D_MODEL; k2 += 256) vmean[k2] = 0.f;
  }
  if (tid < U) {
    uint32_t o0, o1;
    threefry2x32(k0, k1, 0u, (uint32_t)(l * U + tid), &o0, &o1);
    idxl[tid] = (int)((o0 ^ o1) & (uint32_t)(L - 1));
  }
  int h = lane >> 3;
  const float4* qr = (const float4*)(Q + (size_t)bl * D_MODEL + lane * 8);
  float4 q0 = qr[0], q1 = qr[1];
  float qv[8] = {q0.x, q0.y, q0.z, q0.w, q1.x, q1.y, q1.z, q1.w};
  __syncthreads();
  float mx = -INFINITY, sm = 0.f;
  for (int u = wave; u < U; u += 4) {
    int ki = idxl[u];
    short8 k8 = *(const short8*)(K16 + ((size_t)b * L + ki) * D_MODEL + lane * 8);
    float p = 0.f;
#pragma unroll
    for (int e = 0; e < 8; ++e) p += qv[e] * bf2f((unsigned short)k8[e]);
    p += __shfl_xor(p, 1);
    p += __shfl_xor(p, 2);
    p += __shfl_xor(p, 4);
    mx = fmaxf(mx, p);
    sm += p;
  }
  if ((lane & 7) == 0) { wmax[wave][h] = mx; wsum[wave][h] = sm; }
  __syncthreads();
  if (tid < 8) {
    float m = fmaxf(fmaxf(wmax[0][tid], wmax[1][tid]),
                    fmaxf(wmax[2][tid], wmax[3][tid]));
    float s = wsum[0][tid] + wsum[1][tid] + wsum[2][tid] + wsum[3][tid];
    Mout[((size_t)(b * NH + tid)) * L + l] = m - s / (float)L;
  }
}

// ------- top-k (ballot order-statistics) + bitmap + vmean partial ---------
// blocks [0,32): topk per bh; blocks [32, 32+64*B): vmean partial chunks.
template <int NE>  // NE = L/256 elems per lane
__global__ __launch_bounds__(256) void topk_vmean_kernel(
    const float* __restrict__ Mv, const float* __restrict__ Q,
    const float* __restrict__ V, float* __restrict__ vmean,
    int* __restrict__ Mtop, unsigned int* __restrict__ bmap,
    unsigned short* __restrict__ qred16, int words, int u, int L) {
  int blk = blockIdx.x;
  int t = threadIdx.x;
  if (blk >= 32) {
    // vmean partial: 64 chunks x B batches (vmean zeroed in prior dispatch)
    int idx = blk - 32;
    int b2 = idx >> 6, chunk = idx & 63;
    int rows = L >> 6;
    const float* base = V + ((size_t)b2 * L + (size_t)chunk * rows) * D_MODEL;
    float s0 = 0.f, s1 = 0.f;
    for (int r = 0; r < rows; ++r) {
      s0 += base[(size_t)r * D_MODEL + t];
      s1 += base[(size_t)r * D_MODEL + t + 256];
    }
    float invL = 1.0f / (float)L;
    atomicAdd(&vmean[b2 * D_MODEL + t], s0 * invL);
    atomicAdd(&vmean[b2 * D_MODEL + t + 256], s1 * invL);
    return;
  }
  int bh = blk;
  int b = bh >> 3, h = bh & 7;
  int wave = t >> 6, lane = t & 63;
  const int base = wave * 64 * NE;
  const float* src = Mv + (size_t)bh * (NE * 256);
  uint32_t ov[NE];
#pragma unroll
  for (int i = 0; i < NE; ++i) {
    uint32_t bits = __float_as_uint(src[base + i * 64 + lane]);
    uint32_t m = (uint32_t)((int32_t)bits >> 31) | 0x80000000u;
    ov[i] = bits ^ m;
  }
  if (t < words) bmap[bh * words + t] = 0u;
  uint32_t T = 0;
  for (int bit = 31; bit >= 0; --bit) {
    uint32_t cand = T | (1u << bit);
    int c = 0;
#pragma unroll
    for (int i = 0; i < NE; ++i)
      c += (int)__popcll(__ballot(ov[i] >= cand));
    if (c >= u) T = cand;
  }
  int c_gt = 0;
#pragma unroll
  for (int i = 0; i < NE; ++i)
    c_gt += (int)__popcll(__ballot(ov[i] > T));
  int need = u - c_gt;
  int I = 0;
  for (int bit = 10; bit >= 0; --bit) {
    int cand = I | (1 << bit);
    int c = 0;
#pragma unroll
    for (int i = 0; i < NE; ++i)
      c += (int)__popcll(__ballot(ov[i] == T && (base + i * 64 + lane) < cand));
    if (c < need) I = cand;
  }
  __shared__ uint32_t kOrd[160];
  __shared__ int kIdx[160];
  __shared__ int smTop[40];
  int cnt_pre = 0;
#pragma unroll
  for (int i = 0; i < NE; ++i) {
    int ix = base + i * 64 + lane;
    bool sel = (ov[i] > T) || (ov[i] == T && ix <= I);
    unsigned long long bal = __ballot(sel);
    if (sel) {
      int pos = wave * u + cnt_pre +
                (int)__popcll(bal & ((1ull << lane) - 1ull));
      kOrd[pos] = ov[i];
      kIdx[pos] = ix;
    }
    cnt_pre += (int)__popcll(bal);
  }
  __syncthreads();
  int total = 4 * u;
  if (t < total) {
    uint32_t myo = kOrd[t];
    int myi = kIdx[t];
    int rank = 0;
    for (int j = 0; j < total; ++j) {
      uint32_t jo = kOrd[j];
      int ji = kIdx[j];
      rank += (jo > myo || (jo == myo && ji < myi)) ? 1 : 0;
    }
    if (rank < u) {
      Mtop[bh * u + rank] = myi;
      smTop[rank] = myi;
      atomicOr(&bmap[bh * words + (myi >> 5)], 1u << (myi & 31));
    }
  }
  __syncthreads();
  int d = t & 63;
  for (int r = t >> 6; r < 64; r += 4) {
    float v = 0.f;
    if (r < u) {
      int l = smTop[r];
      v = Q[((size_t)(b * L + l)) * D_MODEL + h * DH + d];
    }
    qred16[((size_t)bh * 64 + r) * 64 + d] = f2bf(v);
  }
}

static void run_topk(const float* Mv, const float* Q, const float* V,
                     float* vmean, int* Mtop, unsigned int* bmap,
                     unsigned short* qred16, int L, int u, int B,
                     hipStream_t stream) {
  int words = L / 32;
  int nblk = 32 + 64 * B;
  if (L == 2048)
    topk_vmean_kernel<8><<<nblk, 256, 0, stream>>>(Mv, Q, V, vmean, Mtop, bmap, qred16, words, u, L);
  else if (L == 1024)
    topk_vmean_kernel<4><<<nblk, 256, 0, stream>>>(Mv, Q, V, vmean, Mtop, bmap, qred16, words, u, L);
  else
    topk_vmean_kernel<2><<<nblk, 256, 0, stream>>>(Mv, Q, V, vmean, Mtop, bmap, qred16, words, u, L);
}

// ctx fill: bf16 ctx everywhere + fp32 ZERO only for selected segs
// (the pv atomic accumulation base). Verified R8 structure.
__global__ void fill_ctx_kernel(const float* __restrict__ vmean,
                                const unsigned int* __restrict__ bmap,
                                unsigned short* __restrict__ O16,
                                float* __restrict__ O32, int B, int L,
                                int words) {
  int i = blockIdx.x * 256 + threadIdx.x;
  int total = B * L * D_MODEL;
  if (i >= total) return;
  int dcol = i % D_MODEL;
  int l = (i / D_MODEL) % L;
  int b = i / (D_MODEL * L);
  int h = dcol >> 6;
  unsigned int w = bmap[(b * NH + h) * words + (l >> 5)];
  bool sel = (w >> (l & 31)) & 1u;
  O16[i] = f2bf(sel ? 0.f : vmean[b * D_MODEL + dcol]);
  if (sel) O32[i] = 0.f;
}

// post-pv: recast ONLY the selected segments fp32 -> bf16
__global__ void cast_sel_kernel(const float* __restrict__ O32,
                                const int* __restrict__ Mtop,
                                unsigned short* __restrict__ O16, int L,
                                int U) {
  int z = blockIdx.x;
  int b = z >> 3, h = z & 7;
  int t = threadIdx.x;
  int d = t & 63;
  for (int r = t >> 6; r < U; r += 4) {
    int l = Mtop[z * U + r];
    size_t off = ((size_t)(b * L + l)) * D_MODEL + h * DH + d;
    O16[off] = f2bf(O32[off]);
  }
}

// S[z][U][L] = 0.125 * Qred16[z] @ K16_z^T (rows >= U not written)
__global__ __launch_bounds__(256) void scores_mfma_kernel(
    const unsigned short* __restrict__ qred16,
    const unsigned short* __restrict__ k16, float* __restrict__ S, int L,
    int U) {
  __shared__ unsigned short lds[16384];
  const int z = blockIdx.y;
  const int b = z >> 3, h = z & 7;
  const int bn = blockIdx.x * 64;
  const int tid = threadIdx.x;
  Acc4 acc;
  gemm64_core(qred16 + (size_t)z * 4096, 64,
              k16 + (size_t)b * L * D_MODEL + h * DH, D_MODEL, 64, 0, bn, lds,
              tid, acc);
  float* Sz = S + (size_t)z * 64 * L;
  const int wave = tid >> 6, lane = tid & 63;
  const int wm = (wave >> 1) * 32, wn = (wave & 1) * 32;
  const int quad = lane >> 4, l16 = lane & 15;
#pragma unroll
  for (int i = 0; i < 2; ++i) {
#pragma unroll
    for (int j = 0; j < 2; ++j) {
      int col = bn + wn + j * 16 + l16;
#pragma unroll
      for (int p = 0; p < 4; ++p) {
        int row = wm + i * 16 + quad * 4 + p;
        if (row < U) Sz[(size_t)row * L + col] = 0.125f * acc.v[i][j][p];
      }
    }
  }
}

// ---------------- softmax stats (m, 1/l) only; no P write-back ------------
template <int LC>
__global__ __launch_bounds__(256) void softmax_stats_kernel(
    const float* __restrict__ S, float* __restrict__ mrow,
    float* __restrict__ lrow, int U) {
  constexpr int NE = LC / 256;
  int rid = blockIdx.x;
  int z = rid / U, r = rid % U;
  const float* row = S + (size_t)z * 64 * LC + (size_t)r * LC;
  int t = threadIdx.x;
  float vals[NE];
  float m = -INFINITY;
#pragma unroll
  for (int i = 0; i < NE; ++i) {
    vals[i] = row[t + i * 256];
    m = fmaxf(m, vals[i]);
  }
  __shared__ float red[256];
  red[t] = m;
  __syncthreads();
  for (int s = 128; s > 0; s >>= 1) { if (t < s) red[t] = fmaxf(red[t], red[t + s]); __syncthreads(); }
  m = red[0];
  __syncthreads();
  float sum = 0.f;
#pragma unroll
  for (int i = 0; i < NE; ++i) sum += expf(vals[i] - m);
  red[t] = sum;
  __syncthreads();
  for (int s = 128; s > 0; s >>= 1) { if (t < s) red[t] += red[t + s]; __syncthreads(); }
  if (t == 0) {
    mrow[z * 64 + r] = m;
    lrow[z * 64 + r] = 1.0f / red[0];
  }
}

static void run_stats(const float* S, float* mrow, float* lrow, int L, int U,
                      hipStream_t stream) {
  int blocks = 32 * U;
  if (L == 2048)      softmax_stats_kernel<2048><<<blocks, 256, 0, stream>>>(S, mrow, lrow, U);
  else if (L == 1024) softmax_stats_kernel<1024><<<blocks, 256, 0, stream>>>(S, mrow, lrow, U);
  else                softmax_stats_kernel<512><<<blocks, 256, 0, stream>>>(S, mrow, lrow, U);
}

// O[sel rows] += softmax(S) @ V, split-K over 128-chunks of L.
// P computed on the fly: exp(s - m_r) * inv_r.  Verified R8 structure.
#define PV_LC 128

template <int U>
__global__ __launch_bounds__(256) void pv_kernel(
    const float* __restrict__ P, const float* __restrict__ V,
    const float* __restrict__ mrow, const float* __restrict__ lrow,
    const int* __restrict__ Mtop, float* __restrict__ O, int L) {
  __shared__ float Pl[U][PV_LC];
  __shared__ float Vl[PV_LC][DH + 4];
  __shared__ float Msh[U], Ish[U];
  const int z = blockIdx.y;
  const int b = z / NH, h = z % NH;
  const int c0 = blockIdx.x * PV_LC;
  const int tid = threadIdx.x;
  if (tid < U) { Msh[tid] = mrow[z * 64 + tid]; Ish[tid] = lrow[z * 64 + tid]; }
  __syncthreads();
  const float* Pz = P + (size_t)z * 64 * L + c0;
  for (int i4 = tid; i4 < U * (PV_LC / 4); i4 += 256) {
    int r = i4 / (PV_LC / 4);
    int lq = (i4 % (PV_LC / 4)) * 4;
    float4 p4 = *(const float4*)(Pz + (size_t)r * L + lq);
    float mr = Msh[r], ir = Ish[r];
    Pl[r][lq + 0] = expf(p4.x - mr) * ir;
    Pl[r][lq + 1] = expf(p4.y - mr) * ir;
    Pl[r][lq + 2] = expf(p4.z - mr) * ir;
    Pl[r][lq + 3] = expf(p4.w - mr) * ir;
  }
  const float* Vb = V + ((size_t)b * L + c0) * D_MODEL + h * DH;
  for (int i4 = tid; i4 < PV_LC * (DH / 4); i4 += 256) {
    int l = i4 >> 4;
    int d4 = (i4 & 15) * 4;
    float4 v4 = *(const float4*)(Vb + (size_t)l * D_MODEL + d4);
    Vl[l][d4 + 0] = v4.x; Vl[l][d4 + 1] = v4.y;
    Vl[l][d4 + 2] = v4.z; Vl[l][d4 + 3] = v4.w;
  }
  __syncthreads();
  const int wave = tid >> 6, lane = tid & 63;
  constexpr int NJ = (U + 3) / 4;
  float acc[NJ] = {};
  for (int l = 0; l < PV_LC; ++l) {
    float vv = Vl[l][lane];
#pragma unroll
    for (int j = 0; j < NJ; ++j) {
      int r = wave + 4 * j;
      if (r < U) acc[j] += Pl[r][l] * vv;
    }
  }
#pragma unroll
  for (int j = 0; j < NJ; ++j) {
    int r = wave + 4 * j;
    if (r < U) {
      int ml = Mtop[z * U + r];
      atomicAdd(&O[((size_t)(b * L + ml)) * D_MODEL + h * DH + lane], acc[j]);
    }
  }
}

static void run_pv(const float* P, const float* V, const float* mrow,
                   const float* lrow, const int* Mtop, float* O, int L, int U,
                   hipStream_t stream) {
  dim3 gg(L / PV_LC, 32);
  if (U == 40)      pv_kernel<40><<<gg, 256, 0, stream>>>(P, V, mrow, lrow, Mtop, O, L);
  else if (U == 35) pv_kernel<35><<<gg, 256, 0, stream>>>(P, V, mrow, lrow, Mtop, O, L);
  else              pv_kernel<64><<<gg, 256, 0, stream>>>(P, V, mrow, lrow, Mtop, O, L);
}

// ---------------- maxpool k=3 s=2, dual fp32/bf16 out ---------------------
__global__ void maxpool_kernel(const float* __restrict__ Y,
                               float* __restrict__ X,
                               unsigned short* __restrict__ Xb, int B, int L) {
  int Lo = L / 2;
  int i = blockIdx.x * 256 + threadIdx.x;
  int total = B * Lo * D_MODEL;
  if (i >= total) return;
  int d = i % D_MODEL;
  int lp = (i / D_MODEL) % Lo;
  int b = i / (D_MODEL * Lo);
  int l0 = 2 * lp - 1;
  float m = -INFINITY;
#pragma unroll
  for (int k = 0; k < 3; ++k) {
    int l = l0 + k;
    if (l >= 0 && l < L) m = fmaxf(m, Y[((size_t)(b * L + l)) * D_MODEL + d]);
  }
  X[i] = m;
  Xb[i] = f2bf(m);
}

// ==========================================================================
extern "C" void kernel_launch(void* const* d_in, const int* in_sizes, int n_in,
                              void* d_out, int out_size, void* d_ws,
                              size_t ws_size, hipStream_t stream) {
  const float* x_enc  = (const float*)d_in[0];
  const float* emb_w  = (const float*)d_in[1];
  const float* Wq     = (const float*)d_in[2];
  const float* bq     = (const float*)d_in[3];
  const float* Wk     = (const float*)d_in[4];
  const float* bk     = (const float*)d_in[5];
  const float* Wv     = (const float*)d_in[6];
  const float* bv     = (const float*)d_in[7];
  const float* Wo     = (const float*)d_in[8];
  const float* bo     = (const float*)d_in[9];
  const float* ln1_g  = (const float*)d_in[10];
  const float* ln1_b  = (const float*)d_in[11];
  const float* ff_w1  = (const float*)d_in[12];
  const float* ff_b1  = (const float*)d_in[13];
  const float* ff_w2  = (const float*)d_in[14];
  const float* ff_b2  = (const float*)d_in[15];
  const float* ln2_g  = (const float*)d_in[16];
  const float* ln2_b  = (const float*)d_in[17];
  const float* cv_w   = (const float*)d_in[18];
  const float* cv_b   = (const float*)d_in[19];
  const float* bn_g   = (const float*)d_in[20];
  const float* bn_b   = (const float*)d_in[21];
  const float* norm_g = (const float*)d_in[22];
  const float* norm_b = (const float*)d_in[23];

  const int B = 4, L0 = 2048, EL = 3;
  const size_t SZ = (size_t)B * 2048 * 512;
  float* ws   = (float*)d_ws;
  float* xbuf = ws;
  float* ebuf = ws + SZ;   // layer0 xb16; pre-LN temp; Sbuf
  float* qbuf = ws + 2 * SZ;
  float* kbuf = ws + 3 * SZ;   // hosts k16 (bf16 K) per layer
  float* vbuf = ws + 4 * SZ;
  float* obuf = ws + 5 * SZ;   // fp32 ctx accumulation base (selected rows)
  float* sm   = ws + 6 * SZ;
  // scratch region:
  float*         d_M     = sm;                          // 65536
  int*           d_Mtop  = (int*)(sm + 65536);          // 1280
  float*         d_vmean = sm + 65536 + 1280;           // 2048
  unsigned int*  d_bmap  = (unsigned int*)(sm + 65536 + 1280 + 2048);  // 2048
  unsigned short* qred16 = (unsigned short*)(sm + 65536 + 1280 + 2048 + 2048);
  float*         d_mrow  = sm + 136448;                 // 2048
  float*         d_lrow  = sm + 138496;                 // 2048
  // pre-cast bf16 weights region at ws + 6SZ + 160000 floats
  unsigned short* wgt  = (unsigned short*)(ws + 6 * SZ + 160000);
  unsigned short* qkvw = wgt;                    // EL x [Wq;Wk;Wv] (786432 ea)
  unsigned short* wof  = wgt + 3 * 786432;       // [wow | w1w | w2w]
  unsigned short* wow  = wof;
  unsigned short* w1w  = wof + 786432;
  unsigned short* w2w  = wof + 2 * 786432;
  unsigned short* cvw2 = wof + 3 * 786432;       // 2 x 786432 (k*512+c order)

  float* Sbuf = ebuf;
  const float inv_s = 1.0f / sqrtf(1.0f + 1e-5f);

  // ---- upfront weight casts: 3 dispatches ----
  cast3_qkv_kernel<<<3 * 768, 256, 0, stream>>>(Wq, Wk, Wv, qkvw);
  cast3_flat_kernel<<<3 * 768, 256, 0, stream>>>(Wo, ff_w1, ff_w2, wof);
  cast_cvperm_kernel<<<6144, 256, 0, stream>>>(cv_w, cvw2);

  // layer-0 x bf16 fused into embed (-> ebuf)
  embed_kernel<<<ceil_div(B * L0 * D_MODEL, 256), 256, 0, stream>>>(
      x_enc, emb_w, xbuf, (unsigned short*)ebuf, B, L0);
  unsigned short* xb16 = (unsigned short*)ebuf;  // current layer's bf16 x

  int L = L0;
  int log2L = 11;
  for (int i = 0; i < EL; ++i) {
    const int M_ = B * L;
    int c = 5 * (int)ceil(log((double)L));
    int U = c < L ? c : L;
    int words = L / 32;
    unsigned short* k16 = (unsigned short*)kbuf;

    // QKV fused GEMM (64^2 tile, N=1536)
    qkv_gemm_kernel<<<24 * (M_ / 64), 256, 0, stream>>>(
        xb16, qkvw + (size_t)i * 786432, bq + i * 512, bk + i * 512,
        bv + i * 512, qbuf, vbuf, k16, M_, 512);

    uint32_t lk0, lk1, k20, k21;
    threefry2x32(0u, 42u, 0u, (uint32_t)i, &lk0, &lk1);
    threefry2x32(lk0, lk1, 0u, 1u, &k20, &k21);

    // fused idx + gather-dot + M reduce (+vmean zero in block 0)
    sparse_qk_fused_kernel<<<B * L, 256, 0, stream>>>(qbuf, k16, d_M, d_vmean,
                                                      B, L, U, k20, k21);
    // topk + bitmap + qred gather + vmean partial (merged dispatch)
    run_topk(d_M, qbuf, vbuf, d_vmean, d_Mtop, d_bmap, qred16, L, U, B,
             stream);
    // ctx bf16 (vmean / 0-placeholder) + fp32 zeros for selected rows
    unsigned short* ab16 = (unsigned short*)qbuf;
    fill_ctx_kernel<<<ceil_div(B * L * D_MODEL, 256), 256, 0, stream>>>(
        d_vmean, d_bmap, ab16, obuf, B, L, words);

    scores_mfma_kernel<<<dim3(L / 64, B * NH), 256, 0, stream>>>(qred16, k16,
                                                                 Sbuf, L, U);
    run_stats(Sbuf, d_mrow, d_lrow, L, U, stream);
    run_pv(Sbuf, vbuf, d_mrow, d_lrow, d_Mtop, obuf, L, U, stream);
    // recast selected segments into the bf16 ctx
    cast_sel_kernel<<<B * NH, 256, 0, stream>>>(obuf, d_Mtop, ab16, L, U);

    // O-proj (+residual) -> ebuf fp32
    run_bgemm<2, 1>(ab16, wow + (size_t)i * 262144, bo + i * 512, xbuf,
                    nullptr, nullptr, ebuf, nullptr, M_, 512, 512, 0.f,
                    stream);
    // ln1 dual-writes x fp32 + bf16 (FF1 A input) -> qbuf shorts
    ln_dual_kernel<<<M_, 256, 0, stream>>>(ebuf, ln1_g + i * 512,
                                           ln1_b + i * 512, xbuf, ab16);

    // FF1: bf16-only output -> obuf shorts
    unsigned short* ff1b16 = (unsigned short*)obuf;
    run_bgemm<1, 2>(ab16, w1w + (size_t)i * 262144, ff_b1 + i * 512, nullptr,
                    nullptr, nullptr, nullptr, ff1b16, M_, 512, 512, 0.f,
                    stream);
    // FF2 (+residual) -> ebuf fp32
    run_bgemm<2, 1>(ff1b16, w2w + (size_t)i * 262144, ff_b2 + i * 512, xbuf,
                    nullptr, nullptr, ebuf, nullptr, M_, 512, 512, 0.f,
                    stream);

    if (i < EL - 1) {
      // ln2 dual: fp32 -> xbuf, bf16 -> qbuf (conv GEMM A)
      unsigned short* xln16 = (unsigned short*)qbuf;
      ln_dual_kernel<<<M_, 256, 0, stream>>>(ebuf, ln2_g + i * 512,
                                             ln2_b + i * 512, xbuf, xln16);
      // conv distill as shifted-K GEMM
      conv_gemm_kernel<<<8 * (M_ / 64), 256, 0, stream>>>(
          xln16, cvw2 + (size_t)i * 786432, cv_b + i * 512, bn_g + i * 512,
          bn_b + i * 512, ebuf, M_, L, log2L, inv_s);
      // maxpool dual-writes next-layer x fp32 + bf16 @ vbuf tail
      xb16 = (unsigned short*)vbuf + 6291456;  // byte offset 12.6MB
      maxpool_kernel<<<ceil_div(B * (L / 2) * D_MODEL, 256), 256, 0, stream>>>(
          ebuf, xbuf, xb16, B, L);
      L /= 2;
      log2L -= 1;
    } else {
      ln_kernel<<<M_, 256, 0, stream>>>(ebuf, ln2_g + i * 512,
                                        ln2_b + i * 512, xbuf);
    }
  }

  ln_kernel<<<B * L, 256, 0, stream>>>(xbuf, norm_g, norm_b, (float*)d_out);
}

// Round 12
// 659.792 us; speedup vs baseline: 2.1311x; 1.0281x over previous
//
#include <hip/hip_runtime.h>
#include <cmath>
#include <cstdint>

#define D_MODEL 512
#define NH 8
#define DH 64

static inline int ceil_div(int a, int b) { return (a + b - 1) / b; }

typedef __attribute__((ext_vector_type(8))) short short8;
typedef __attribute__((ext_vector_type(4))) float floatx4;

// fp32 -> bf16 (RNE)
__device__ __forceinline__ unsigned short f2bf(float f) {
  uint32_t u = __float_as_uint(f);
  uint32_t r = (u + 0x7fffu + ((u >> 16) & 1u)) >> 16;
  return (unsigned short)r;
}
__device__ __forceinline__ float bf2f(unsigned short s) {
  return __uint_as_float(((uint32_t)s) << 16);
}

// ---------------- threefry2x32 (JAX-exact) ----------------
#define TF_ROTL(x, r) (((x) << (r)) | ((x) >> (32 - (r))))

__host__ __device__ inline void threefry2x32(uint32_t k0, uint32_t k1,
                                             uint32_t x0, uint32_t x1,
                                             uint32_t* o0, uint32_t* o1) {
  uint32_t ks2 = k0 ^ k1 ^ 0x1BD11BDAu;
  x0 += k0; x1 += k1;
#define TF_R4(a, b, c, d)                                    \
  x0 += x1; x1 = TF_ROTL(x1, a); x1 ^= x0;                   \
  x0 += x1; x1 = TF_ROTL(x1, b); x1 ^= x0;                   \
  x0 += x1; x1 = TF_ROTL(x1, c); x1 ^= x0;                   \
  x0 += x1; x1 = TF_ROTL(x1, d); x1 ^= x0;
  TF_R4(13, 15, 26, 6);  x0 += k1;  x1 += ks2 + 1u;
  TF_R4(17, 29, 16, 24); x0 += ks2; x1 += k0 + 2u;
  TF_R4(13, 15, 26, 6);  x0 += k0;  x1 += k1 + 3u;
  TF_R4(17, 29, 16, 24); x0 += k1;  x1 += ks2 + 4u;
  TF_R4(13, 15, 26, 6);  x0 += ks2; x1 += k0 + 5u;
#undef TF_R4
  *o0 = x0; *o1 = x1;
}

// ---------------- ALL upfront weight casts in ONE dispatch ----------------
// blocks [0,2304): qkv interleave cast; [2304,4608): flat [Wo|w1|w2];
// [4608,10752): conv permute-cast.
__global__ __launch_bounds__(256) void cast_all_kernel(
    const float* __restrict__ Wq, const float* __restrict__ Wk,
    const float* __restrict__ Wv, unsigned short* __restrict__ qkvw,
    const float* __restrict__ Wo, const float* __restrict__ w1,
    const float* __restrict__ w2, unsigned short* __restrict__ wof,
    const float* __restrict__ cv, unsigned short* __restrict__ cvw2) {
  int blk = blockIdx.x;
  int tid = threadIdx.x;
  if (blk < 2304) {
    int sel = blk / 768, bb = blk % 768;
    int i = (bb * 256 + tid) * 4;  // < 786432
    const float* s = (sel == 0) ? Wq : (sel == 1) ? Wk : Wv;
    float4 v = *(const float4*)(s + i);
    ushort4 o;
    o.x = f2bf(v.x); o.y = f2bf(v.y); o.z = f2bf(v.z); o.w = f2bf(v.w);
    int layer = i >> 18, off = i & 262143;
    *(ushort4*)(qkvw + (size_t)layer * 786432 + sel * 262144 + off) = o;
  } else if (blk < 4608) {
    int sub = blk - 2304;
    int sel = sub / 768, bb = sub % 768;
    int i = (bb * 256 + tid) * 4;
    const float* s = (sel == 0) ? Wo : (sel == 1) ? w1 : w2;
    float4 v = *(const float4*)(s + i);
    ushort4 o;
    o.x = f2bf(v.x); o.y = f2bf(v.y); o.z = f2bf(v.z); o.w = f2bf(v.w);
    *(ushort4*)(wof + (size_t)sel * 786432 + i) = o;
  } else {
    int o = (blk - 4608) * 256 + tid;  // < 2*786432
    int m = o / 786432, rem = o % 786432;
    int n = rem / 1536, q = rem % 1536;
    int k = q >> 9, c = q & 511;
    cvw2[o] = f2bf(cv[(size_t)m * 786432 + n * 1536 + c * 3 + k]);
  }
}

// ---------------- embedding + pos encoding, dual fp32/bf16 out ------------
__global__ __launch_bounds__(256) void embed_kernel(
    const float* __restrict__ x_enc, const float* __restrict__ emb_w,
    float* __restrict__ x, unsigned short* __restrict__ xb, int B, int L) {
  int i = blockIdx.x * 256 + threadIdx.x;
  int total = B * L * D_MODEL;
  if (i >= total) return;
  int d = i % D_MODEL;
  int l = (i / D_MODEL) % L;
  int b = i / (D_MODEL * L);
  int lm = (l == 0) ? (L - 1) : (l - 1);
  int lp = (l == L - 1) ? 0 : (l + 1);
  const float* w = emb_w + d * 6;
  const float* xb_in = x_enc + (size_t)b * L * 2;
  float acc = 0.f;
  acc += xb_in[lm * 2 + 0] * w[0] + xb_in[l * 2 + 0] * w[1] + xb_in[lp * 2 + 0] * w[2];
  acc += xb_in[lm * 2 + 1] * w[3] + xb_in[l * 2 + 1] * w[4] + xb_in[lp * 2 + 1] * w[5];
  int j = d >> 1;
  const float coef = -0.017988946039015985f;  // -ln(10000)/512
  float div = expf((float)(2 * j) * coef);
  float ang = (float)l * div;
  float pe = (d & 1) ? cosf(ang) : sinf(ang);
  float v = acc + pe;
  x[i] = v;
  xb[i] = f2bf(v);
}

// ---------------- layer norm over D=512 (plain + dual-output) -------------
__global__ __launch_bounds__(256) void ln_kernel(
    const float* __restrict__ in, const float* __restrict__ g,
    const float* __restrict__ b, float* __restrict__ out) {
  int row = blockIdx.x;
  int t = threadIdx.x;
  const float* xr = in + (size_t)row * D_MODEL;
  float v0 = xr[t], v1 = xr[t + 256];
  __shared__ float red[256];
  red[t] = v0 + v1;
  __syncthreads();
  for (int s = 128; s > 0; s >>= 1) { if (t < s) red[t] += red[t + s]; __syncthreads(); }
  float mean = red[0] * (1.0f / 512.0f);
  __syncthreads();
  float d0 = v0 - mean, d1 = v1 - mean;
  red[t] = d0 * d0 + d1 * d1;
  __syncthreads();
  for (int s = 128; s > 0; s >>= 1) { if (t < s) red[t] += red[t + s]; __syncthreads(); }
  float var = red[0] * (1.0f / 512.0f);
  float rstd = 1.0f / sqrtf(var + 1e-5f);
  float* outr = out + (size_t)row * D_MODEL;
  outr[t]       = d0 * rstd * g[t]       + b[t];
  outr[t + 256] = d1 * rstd * g[t + 256] + b[t + 256];
}

__global__ __launch_bounds__(256) void ln_dual_kernel(
    const float* __restrict__ in, const float* __restrict__ g,
    const float* __restrict__ b, float* __restrict__ out,
    unsigned short* __restrict__ out16) {
  int row = blockIdx.x;
  int t = threadIdx.x;
  const float* xr = in + (size_t)row * D_MODEL;
  float v0 = xr[t], v1 = xr[t + 256];
  __shared__ float red[256];
  red[t] = v0 + v1;
  __syncthreads();
  for (int s = 128; s > 0; s >>= 1) { if (t < s) red[t] += red[t + s]; __syncthreads(); }
  float mean = red[0] * (1.0f / 512.0f);
  __syncthreads();
  float d0 = v0 - mean, d1 = v1 - mean;
  red[t] = d0 * d0 + d1 * d1;
  __syncthreads();
  for (int s = 128; s > 0; s >>= 1) { if (t < s) red[t] += red[t + s]; __syncthreads(); }
  float var = red[0] * (1.0f / 512.0f);
  float rstd = 1.0f / sqrtf(var + 1e-5f);
  float* outr = out + (size_t)row * D_MODEL;
  unsigned short* o16 = out16 + (size_t)row * D_MODEL;
  float r0 = d0 * rstd * g[t] + b[t];
  float r1 = d1 * rstd * g[t + 256] + b[t + 256];
  outr[t] = r0;       o16[t] = f2bf(r0);
  outr[t + 256] = r1; o16[t + 256] = f2bf(r1);
}

// MODE 0: +bias   1: gelu(+bias)   2: +bias +R   3: elu((+bias)*scl*g + bb)
__device__ __forceinline__ float epilogue_apply(int MODE, float v, float r,
                                                float g, float bb, float scl) {
  if (MODE == 1) {
    v = 0.5f * v * (1.0f + erff(v * 0.7071067811865475f));
  } else if (MODE == 2) {
    v += r;
  } else if (MODE == 3) {
    v = v * scl * g + bb;
    v = (v > 0.f) ? v : expm1f(v);
  }
  return v;
}

// ================= bf16 MFMA GEMM core (64x64, dbuf — verified R6) ========

__device__ __forceinline__ void gload16(const void* g, void* l) {
  __builtin_amdgcn_global_load_lds(
      (const __attribute__((address_space(1))) unsigned int*)g,
      (__attribute__((address_space(3))) unsigned int*)l, 16, 0, 0);
}

// bijective XCD-chunked swizzle (m204)
__device__ __forceinline__ int xcd_swz(int orig, int nwg) {
  int q = nwg >> 3, r = nwg & 7;
  int x = orig & 7, o = orig >> 3;
  return (x < r ? x * (q + 1) : r * (q + 1) + (x - r) * q) + o;
}

__device__ __forceinline__ void stage64(const unsigned short* __restrict__ G,
                                        int ldk, int row0, int k0,
                                        unsigned short* lds, int tid) {
  const int wave = tid >> 6;
#pragma unroll
  for (int iss = 0; iss < 2; ++iss) {
    int s = iss * 256 + tid;          // 512 slots of 16B
    int r = s >> 3;
    int cs = (s & 7) ^ (r & 7);
    gload16(G + (size_t)(row0 + r) * ldk + k0 + cs * 8,
            lds + (size_t)(iss * 256 + wave * 64) * 8);
  }
}

// swizzled fragment read: row-major [R][64] shorts, 16B chunk ^= row&7
__device__ __forceinline__ short8 frag64(const unsigned short* t, int row,
                                         int chunk) {
  return *(const short8*)(t + row * 64 + ((chunk ^ (row & 7)) * 8));
}

struct Acc4 { floatx4 v[2][2]; };

__device__ __forceinline__ void gemm64_core(
    const unsigned short* __restrict__ A, int lda,
    const unsigned short* __restrict__ Bt, int ldb, int K, int bm, int bn,
    unsigned short* lds /*16384 shorts*/, int tid, Acc4& out) {
  const int wave = tid >> 6, lane = tid & 63;
  const int wm = (wave >> 1) * 32, wn = (wave & 1) * 32;
  const int quad = lane >> 4, l16 = lane & 15;
  floatx4 z = {0.f, 0.f, 0.f, 0.f};
  floatx4 a00 = z, a01 = z, a10 = z, a11 = z;
  stage64(A, lda, bm, 0, lds, tid);
  stage64(Bt, ldb, bn, 0, lds + 4096, tid);
  __syncthreads();
  const int nk = K >> 6;
  for (int t = 0; t < nk; ++t) {
    const int cur = (t & 1) * 8192;
    if (t + 1 < nk) {
      const int nxt = 8192 - cur;
      stage64(A, lda, bm, (t + 1) << 6, lds + nxt, tid);
      stage64(Bt, ldb, bn, (t + 1) << 6, lds + nxt + 4096, tid);
    }
    const unsigned short* At = lds + cur;
    const unsigned short* Bl = lds + cur + 4096;
#pragma unroll
    for (int ks = 0; ks < 2; ++ks) {
      short8 f0 = frag64(At, wm + l16,      ks * 4 + quad);
      short8 f1 = frag64(At, wm + 16 + l16, ks * 4 + quad);
      short8 g0 = frag64(Bl, wn + l16,      ks * 4 + quad);
      short8 g1 = frag64(Bl, wn + 16 + l16, ks * 4 + quad);
      a00 = __builtin_amdgcn_mfma_f32_16x16x32_bf16(f0, g0, a00, 0, 0, 0);
      a01 = __builtin_amdgcn_mfma_f32_16x16x32_bf16(f0, g1, a01, 0, 0, 0);
      a10 = __builtin_amdgcn_mfma_f32_16x16x32_bf16(f1, g0, a10, 0, 0, 0);
      a11 = __builtin_amdgcn_mfma_f32_16x16x32_bf16(f1, g1, a11, 0, 0, 0);
    }
    __syncthreads();
  }
  out.v[0][0] = a00; out.v[0][1] = a01; out.v[1][0] = a10; out.v[1][1] = a11;
}

// OUT bitmask: 1 = fp32 C, 2 = bf16 C16
template <int MODE, int OUT>
__global__ __launch_bounds__(256) void bgemm_kernel(
    const unsigned short* __restrict__ A, const unsigned short* __restrict__ Bt,
    const float* __restrict__ bias, const float* __restrict__ R,
    const float* __restrict__ gvec, const float* __restrict__ bvec,
    float* __restrict__ C, unsigned short* __restrict__ C16,
    int M, int N, int K, float scl) {
  __shared__ unsigned short lds[16384];
  const int tid = threadIdx.x;
  const int gridN = N >> 6;
  const int wgid = xcd_swz(blockIdx.x, (int)gridDim.x);
  const int bn = (wgid % gridN) * 64;
  const int bm = (wgid / gridN) * 64;
  Acc4 acc;
  gemm64_core(A, K, Bt, K, K, bm, bn, lds, tid, acc);
  const int wave = tid >> 6, lane = tid & 63;
  const int wm = (wave >> 1) * 32, wn = (wave & 1) * 32;
  const int quad = lane >> 4, l16 = lane & 15;
#pragma unroll
  for (int i = 0; i < 2; ++i) {
#pragma unroll
    for (int j = 0; j < 2; ++j) {
      int col = bn + wn + j * 16 + l16;
#pragma unroll
      for (int p = 0; p < 4; ++p) {
        int row = bm + wm + i * 16 + quad * 4 + p;
        float v = acc.v[i][j][p] + bias[col];
        v = epilogue_apply(MODE, v, (MODE == 2) ? R[(size_t)row * N + col] : 0.f,
                           (MODE == 3) ? gvec[col] : 0.f,
                           (MODE == 3) ? bvec[col] : 0.f, scl);
        if (OUT & 1) C[(size_t)row * N + col] = v;
        if (OUT & 2) C16[(size_t)row * N + col] = f2bf(v);
      }
    }
  }
}

template <int MODE, int OUT>
static void run_bgemm(const unsigned short* A, const unsigned short* Bt,
                      const float* bias, const float* R, const float* g,
                      const float* bb, float* C, unsigned short* C16,
                      int M, int N, int K, float scl, hipStream_t stream) {
  int nwg = (N / 64) * (M / 64);
  bgemm_kernel<MODE, OUT><<<nwg, 256, 0, stream>>>(A, Bt, bias, R, g, bb, C,
                                                   C16, M, N, K, scl);
}

// fused QKV: one M x 1536 x 512 GEMM over concatenated [Wq;Wk;Wv] rows.
// seg 0 -> Q fp32, seg 1 -> K bf16 ONLY (scores+gathers), seg 2 -> V fp32.
__global__ __launch_bounds__(256) void qkv_gemm_kernel(
    const unsigned short* __restrict__ A, const unsigned short* __restrict__ Bt,
    const float* __restrict__ bqp, const float* __restrict__ bkp,
    const float* __restrict__ bvp, float* __restrict__ Cq,
    float* __restrict__ Cv, unsigned short* __restrict__ K16o, int M, int K) {
  __shared__ unsigned short lds[16384];
  const int tid = threadIdx.x;
  const int gridN = 24;  // 1536/64
  const int wgid = xcd_swz(blockIdx.x, (int)gridDim.x);
  const int bn = (wgid % gridN) * 64;
  const int bm = (wgid / gridN) * 64;
  Acc4 acc;
  gemm64_core(A, K, Bt, K, K, bm, bn, lds, tid, acc);
  const int wave = tid >> 6, lane = tid & 63;
  const int wm = (wave >> 1) * 32, wn = (wave & 1) * 32;
  const int quad = lane >> 4, l16 = lane & 15;
#pragma unroll
  for (int i = 0; i < 2; ++i) {
#pragma unroll
    for (int j = 0; j < 2; ++j) {
      int col = bn + wn + j * 16 + l16;
      int seg = col >> 9, nn = col & 511;  // seg uniform per (block,wave,j)
      const float* bp = (seg == 0) ? bqp : (seg == 1) ? bkp : bvp;
      float bsv = bp[nn];
#pragma unroll
      for (int p = 0; p < 4; ++p) {
        int row = bm + wm + i * 16 + quad * 4 + p;
        float v = acc.v[i][j][p] + bsv;
        if (seg == 1) {
          K16o[(size_t)row * 512 + nn] = f2bf(v);
        } else {
          float* Cd = (seg == 0) ? Cq : Cv;
          Cd[(size_t)row * 512 + nn] = v;
        }
      }
    }
  }
}

// conv GEMM (distill): C = elu((A_shift @ Bt + bias) * scl * g + bb)
// A virtual (M x 1536): A[row][k*512+c] = xln16[b, (l+k-1) mod L, c]
__global__ __launch_bounds__(256) void conv_gemm_kernel(
    const unsigned short* __restrict__ Axl, const unsigned short* __restrict__ Bt,
    const float* __restrict__ bias, const float* __restrict__ gvec,
    const float* __restrict__ bvec, float* __restrict__ C,
    int M, int L, int log2L, float scl) {
  __shared__ unsigned short lds[16384];
  const int tid = threadIdx.x;
  const int wgid = xcd_swz(blockIdx.x, (int)gridDim.x);
  const int bn = (wgid & 7) * 64;   // gridN = 8
  const int bm = (wgid >> 3) * 64;
  const int wave = tid >> 6, lane = tid & 63;
  const int wm = (wave >> 1) * 32, wn = (wave & 1) * 32;
  const int quad = lane >> 4, l16 = lane & 15;
  floatx4 z = {0.f, 0.f, 0.f, 0.f};
  floatx4 a00 = z, a01 = z, a10 = z, a11 = z;

#define STAGE_A_CONV(T, DST)                                               \
  {                                                                        \
    _Pragma("unroll") for (int iss = 0; iss < 2; ++iss) {                  \
      int s = iss * 256 + tid;                                             \
      int r = s >> 3;                                                      \
      int cs = (s & 7) ^ (r & 7);                                          \
      int row = bm + r;                                                    \
      int li = row & (L - 1);                                              \
      int bb2 = row >> log2L;                                              \
      int l2 = (li + ((T) >> 3) - 1 + L) & (L - 1);                        \
      gload16(Axl + (((size_t)((bb2 << log2L) + l2)) << 9) +               \
                  (((T) & 7) << 6) + cs * 8,                               \
              (DST) + (size_t)(iss * 256 + wave * 64) * 8);                \
    }                                                                      \
  }

  STAGE_A_CONV(0, lds);
  stage64(Bt, 1536, bn, 0, lds + 4096, tid);
  __syncthreads();
  for (int t = 0; t < 24; ++t) {
    const int cur = (t & 1) * 8192;
    if (t + 1 < 24) {
      const int nxt = 8192 - cur;
      STAGE_A_CONV(t + 1, lds + nxt);
      stage64(Bt, 1536, bn, (t + 1) << 6, lds + nxt + 4096, tid);
    }
    const unsigned short* At = lds + cur;
    const unsigned short* Bl = lds + cur + 4096;
#pragma unroll
    for (int ks = 0; ks < 2; ++ks) {
      short8 f0 = frag64(At, wm + l16,      ks * 4 + quad);
      short8 f1 = frag64(At, wm + 16 + l16, ks * 4 + quad);
      short8 g0 = frag64(Bl, wn + l16,      ks * 4 + quad);
      short8 g1 = frag64(Bl, wn + 16 + l16, ks * 4 + quad);
      a00 = __builtin_amdgcn_mfma_f32_16x16x32_bf16(f0, g0, a00, 0, 0, 0);
      a01 = __builtin_amdgcn_mfma_f32_16x16x32_bf16(f0, g1, a01, 0, 0, 0);
      a10 = __builtin_amdgcn_mfma_f32_16x16x32_bf16(f1, g0, a10, 0, 0, 0);
      a11 = __builtin_amdgcn_mfma_f32_16x16x32_bf16(f1, g1, a11, 0, 0, 0);
    }
    __syncthreads();
  }
#undef STAGE_A_CONV
  floatx4 accs[2][2] = {{a00, a01}, {a10, a11}};
#pragma unroll
  for (int i = 0; i < 2; ++i) {
#pragma unroll
    for (int j = 0; j < 2; ++j) {
      int col = bn + wn + j * 16 + l16;
      float gv = gvec[col], bbv = bvec[col], bsv = bias[col];
#pragma unroll
      for (int p = 0; p < 4; ++p) {
        int row = bm + wm + i * 16 + quad * 4 + p;
        float v = accs[i][j][p] + bsv;
        v = epilogue_apply(3, v, 0.f, gv, bbv, scl);
        C[(size_t)row * 512 + col] = v;
      }
    }
  }
}

// -------- fused sparse QK sampling: idx (threefry) + gather-dot + M-reduce
// block 0 additionally zeroes vmean (consumed by NEXT dispatch -> no race)
__global__ __launch_bounds__(256) void sparse_qk_fused_kernel(
    const float* __restrict__ Q, const unsigned short* __restrict__ K16,
    float* __restrict__ Mout, float* __restrict__ vmean, int B, int L, int U,
    uint32_t k0, uint32_t k1) {
  __shared__ int idxl[64];
  __shared__ float wmax[4][8];
  __shared__ float wsum[4][8];
  int bl = blockIdx.x;  // b*L + l
  int b = bl / L, l = bl - b * L;
  int tid = threadIdx.x;
  int wave = tid >> 6, lane = tid & 63;
  if (bl == 0) {
    for (int k2 = tid; k2 < 4 * D_MODEL; k2 += 256) vmean[k2] = 0.f;
  }
  if (tid < U) {
    uint32_t o0, o1;
    threefry2x32(k0, k1, 0u, (uint32_t)(l * U + tid), &o0, &o1);
    idxl[tid] = (int)((o0 ^ o1) & (uint32_t)(L - 1));
  }
  int h = lane >> 3;
  const float4* qr = (const float4*)(Q + (size_t)bl * D_MODEL + lane * 8);
  float4 q0 = qr[0], q1 = qr[1];
  float qv[8] = {q0.x, q0.y, q0.z, q0.w, q1.x, q1.y, q1.z, q1.w};
  __syncthreads();
  float mx = -INFINITY, sm = 0.f;
  for (int u = wave; u < U; u += 4) {
    int ki = idxl[u];
    short8 k8 = *(const short8*)(K16 + ((size_t)b * L + ki) * D_MODEL + lane * 8);
    float p = 0.f;
#pragma unroll
    for (int e = 0; e < 8; ++e) p += qv[e] * bf2f((unsigned short)k8[e]);
    p += __shfl_xor(p, 1);
    p += __shfl_xor(p, 2);
    p += __shfl_xor(p, 4);
    mx = fmaxf(mx, p);
    sm += p;
  }
  if ((lane & 7) == 0) { wmax[wave][h] = mx; wsum[wave][h] = sm; }
  __syncthreads();
  if (tid < 8) {
    float m = fmaxf(fmaxf(wmax[0][tid], wmax[1][tid]),
                    fmaxf(wmax[2][tid], wmax[3][tid]));
    float s = wsum[0][tid] + wsum[1][tid] + wsum[2][tid] + wsum[3][tid];
    Mout[((size_t)(b * NH + tid)) * L + l] = m - s / (float)L;
  }
}

// ------- top-k (ballot order-statistics) + bitmap + vmean partial ---------
// blocks [0,32): topk per bh; blocks [32, 32+64*B): vmean partial chunks.
template <int NE>  // NE = L/256 elems per lane
__global__ __launch_bounds__(256) void topk_vmean_kernel(
    const float* __restrict__ Mv, const float* __restrict__ Q,
    const float* __restrict__ V, float* __restrict__ vmean,
    int* __restrict__ Mtop, unsigned int* __restrict__ bmap,
    unsigned short* __restrict__ qred16, int words, int u, int L) {
  int blk = blockIdx.x;
  int t = threadIdx.x;
  if (blk >= 32) {
    int idx = blk - 32;
    int b2 = idx >> 6, chunk = idx & 63;
    int rows = L >> 6;
    const float* base = V + ((size_t)b2 * L + (size_t)chunk * rows) * D_MODEL;
    float s0 = 0.f, s1 = 0.f;
    for (int r = 0; r < rows; ++r) {
      s0 += base[(size_t)r * D_MODEL + t];
      s1 += base[(size_t)r * D_MODEL + t + 256];
    }
    float invL = 1.0f / (float)L;
    atomicAdd(&vmean[b2 * D_MODEL + t], s0 * invL);
    atomicAdd(&vmean[b2 * D_MODEL + t + 256], s1 * invL);
    return;
  }
  int bh = blk;
  int b = bh >> 3, h = bh & 7;
  int wave = t >> 6, lane = t & 63;
  const int base = wave * 64 * NE;
  const float* src = Mv + (size_t)bh * (NE * 256);
  uint32_t ov[NE];
#pragma unroll
  for (int i = 0; i < NE; ++i) {
    uint32_t bits = __float_as_uint(src[base + i * 64 + lane]);
    uint32_t m = (uint32_t)((int32_t)bits >> 31) | 0x80000000u;
    ov[i] = bits ^ m;
  }
  if (t < words) bmap[bh * words + t] = 0u;
  uint32_t T = 0;
  for (int bit = 31; bit >= 0; --bit) {
    uint32_t cand = T | (1u << bit);
    int c = 0;
#pragma unroll
    for (int i = 0; i < NE; ++i)
      c += (int)__popcll(__ballot(ov[i] >= cand));
    if (c >= u) T = cand;
  }
  int c_gt = 0;
#pragma unroll
  for (int i = 0; i < NE; ++i)
    c_gt += (int)__popcll(__ballot(ov[i] > T));
  int need = u - c_gt;
  int I = 0;
  for (int bit = 10; bit >= 0; --bit) {
    int cand = I | (1 << bit);
    int c = 0;
#pragma unroll
    for (int i = 0; i < NE; ++i)
      c += (int)__popcll(__ballot(ov[i] == T && (base + i * 64 + lane) < cand));
    if (c < need) I = cand;
  }
  __shared__ uint32_t kOrd[160];
  __shared__ int kIdx[160];
  __shared__ int smTop[40];
  int cnt_pre = 0;
#pragma unroll
  for (int i = 0; i < NE; ++i) {
    int ix = base + i * 64 + lane;
    bool sel = (ov[i] > T) || (ov[i] == T && ix <= I);
    unsigned long long bal = __ballot(sel);
    if (sel) {
      int pos = wave * u + cnt_pre +
                (int)__popcll(bal & ((1ull << lane) - 1ull));
      kOrd[pos] = ov[i];
      kIdx[pos] = ix;
    }
    cnt_pre += (int)__popcll(bal);
  }
  __syncthreads();
  int total = 4 * u;
  if (t < total) {
    uint32_t myo = kOrd[t];
    int myi = kIdx[t];
    int rank = 0;
    for (int j = 0; j < total; ++j) {
      uint32_t jo = kOrd[j];
      int ji = kIdx[j];
      rank += (jo > myo || (jo == myo && ji < myi)) ? 1 : 0;
    }
    if (rank < u) {
      Mtop[bh * u + rank] = myi;
      smTop[rank] = myi;
      atomicOr(&bmap[bh * words + (myi >> 5)], 1u << (myi & 31));
    }
  }
  __syncthreads();
  int d = t & 63;
  for (int r = t >> 6; r < 64; r += 4) {
    float v = 0.f;
    if (r < u) {
      int l = smTop[r];
      v = Q[((size_t)(b * L + l)) * D_MODEL + h * DH + d];
    }
    qred16[((size_t)bh * 64 + r) * 64 + d] = f2bf(v);
  }
}

static void run_topk(const float* Mv, const float* Q, const float* V,
                     float* vmean, int* Mtop, unsigned int* bmap,
                     unsigned short* qred16, int L, int u, int B,
                     hipStream_t stream) {
  int words = L / 32;
  int nblk = 32 + 64 * B;
  if (L == 2048)
    topk_vmean_kernel<8><<<nblk, 256, 0, stream>>>(Mv, Q, V, vmean, Mtop, bmap, qred16, words, u, L);
  else if (L == 1024)
    topk_vmean_kernel<4><<<nblk, 256, 0, stream>>>(Mv, Q, V, vmean, Mtop, bmap, qred16, words, u, L);
  else
    topk_vmean_kernel<2><<<nblk, 256, 0, stream>>>(Mv, Q, V, vmean, Mtop, bmap, qred16, words, u, L);
}

// --- scores (MFMA) + ctx fill, merged dispatch -----------------------------
// blocks [0, nS): S[z][U][L] tiles.  blocks [nS, nS+nF): ctx fill (x4 vec).
// No intra-dispatch dependency: scores reads qred16/k16; fill reads
// bmap/vmean, writes O16 (qbuf) + fp32 zeros (obuf) which scores never uses.
__global__ __launch_bounds__(256) void scores_fill_kernel(
    const unsigned short* __restrict__ qred16,
    const unsigned short* __restrict__ k16, float* __restrict__ S,
    const float* __restrict__ vmean, const unsigned int* __restrict__ bmap,
    unsigned short* __restrict__ O16, float* __restrict__ O32, int B, int L,
    int U, int words, int nS) {
  __shared__ unsigned short lds[16384];
  const int blk = blockIdx.x;
  const int tid = threadIdx.x;
  if (blk >= nS) {
    // ---- ctx fill: 4 elems/thread, same h for all 4 (64 % 4 == 0) ----
    int i4 = ((blk - nS) * 256 + tid) * 4;
    int total = B * L * D_MODEL;
    if (i4 >= total) return;
    int dcol = i4 & 511;
    int l = (i4 >> 9) % L;
    int b = i4 / (D_MODEL * L);
    int h = dcol >> 6;
    unsigned int w = bmap[(b * NH + h) * words + (l >> 5)];
    bool sel = (w >> (l & 31)) & 1u;
    const float* vm = vmean + b * D_MODEL + dcol;
    ushort4 o;
    if (sel) {
      o.x = 0; o.y = 0; o.z = 0; o.w = 0;
      *(float4*)(O32 + i4) = make_float4(0.f, 0.f, 0.f, 0.f);
    } else {
      o.x = f2bf(vm[0]); o.y = f2bf(vm[1]);
      o.z = f2bf(vm[2]); o.w = f2bf(vm[3]);
    }
    *(ushort4*)(O16 + i4) = o;
    return;
  }
  const int gridX = L >> 6;
  const int z = blk / gridX;
  const int bn = (blk % gridX) * 64;
  const int b = z >> 3, h = z & 7;
  Acc4 acc;
  gemm64_core(qred16 + (size_t)z * 4096, 64,
              k16 + (size_t)b * L * D_MODEL + h * DH, D_MODEL, 64, 0, bn, lds,
              tid, acc);
  float* Sz = S + (size_t)z * 64 * L;
  const int wave = tid >> 6, lane = tid & 63;
  const int wm = (wave >> 1) * 32, wn = (wave & 1) * 32;
  const int quad = lane >> 4, l16 = lane & 15;
#pragma unroll
  for (int i = 0; i < 2; ++i) {
#pragma unroll
    for (int j = 0; j < 2; ++j) {
      int col = bn + wn + j * 16 + l16;
#pragma unroll
      for (int p = 0; p < 4; ++p) {
        int row = wm + i * 16 + quad * 4 + p;
        if (row < U) Sz[(size_t)row * L + col] = 0.125f * acc.v[i][j][p];
      }
    }
  }
}

// ---------------- softmax stats (m, 1/l) only; no P write-back ------------
template <int LC>
__global__ __launch_bounds__(256) void softmax_stats_kernel(
    const float* __restrict__ S, float* __restrict__ mrow,
    float* __restrict__ lrow, int U) {
  constexpr int NE = LC / 256;
  int rid = blockIdx.x;
  int z = rid / U, r = rid % U;
  const float* row = S + (size_t)z * 64 * LC + (size_t)r * LC;
  int t = threadIdx.x;
  float vals[NE];
  float m = -INFINITY;
#pragma unroll
  for (int i = 0; i < NE; ++i) {
    vals[i] = row[t + i * 256];
    m = fmaxf(m, vals[i]);
  }
  __shared__ float red[256];
  red[t] = m;
  __syncthreads();
  for (int s = 128; s > 0; s >>= 1) { if (t < s) red[t] = fmaxf(red[t], red[t + s]); __syncthreads(); }
  m = red[0];
  __syncthreads();
  float sum = 0.f;
#pragma unroll
  for (int i = 0; i < NE; ++i) sum += expf(vals[i] - m);
  red[t] = sum;
  __syncthreads();
  for (int s = 128; s > 0; s >>= 1) { if (t < s) red[t] += red[t + s]; __syncthreads(); }
  if (t == 0) {
    mrow[z * 64 + r] = m;
    lrow[z * 64 + r] = 1.0f / red[0];
  }
}

static void run_stats(const float* S, float* mrow, float* lrow, int L, int U,
                      hipStream_t stream) {
  int blocks = 32 * U;
  if (L == 2048)      softmax_stats_kernel<2048><<<blocks, 256, 0, stream>>>(S, mrow, lrow, U);
  else if (L == 1024) softmax_stats_kernel<1024><<<blocks, 256, 0, stream>>>(S, mrow, lrow, U);
  else                softmax_stats_kernel<512><<<blocks, 256, 0, stream>>>(S, mrow, lrow, U);
}

// O[sel rows] += softmax(S) @ V, split-K over 128-chunks of L.
#define PV_LC 128

template <int U>
__global__ __launch_bounds__(256) void pv_kernel(
    const float* __restrict__ P, const float* __restrict__ V,
    const float* __restrict__ mrow, const float* __restrict__ lrow,
    const int* __restrict__ Mtop, float* __restrict__ O, int L) {
  __shared__ float Pl[U][PV_LC];
  __shared__ float Vl[PV_LC][DH + 4];
  __shared__ float Msh[U], Ish[U];
  const int z = blockIdx.y;
  const int b = z / NH, h = z % NH;
  const int c0 = blockIdx.x * PV_LC;
  const int tid = threadIdx.x;
  if (tid < U) { Msh[tid] = mrow[z * 64 + tid]; Ish[tid] = lrow[z * 64 + tid]; }
  __syncthreads();
  const float* Pz = P + (size_t)z * 64 * L + c0;
  for (int i4 = tid; i4 < U * (PV_LC / 4); i4 += 256) {
    int r = i4 / (PV_LC / 4);
    int lq = (i4 % (PV_LC / 4)) * 4;
    float4 p4 = *(const float4*)(Pz + (size_t)r * L + lq);
    float mr = Msh[r], ir = Ish[r];
    Pl[r][lq + 0] = expf(p4.x - mr) * ir;
    Pl[r][lq + 1] = expf(p4.y - mr) * ir;
    Pl[r][lq + 2] = expf(p4.z - mr) * ir;
    Pl[r][lq + 3] = expf(p4.w - mr) * ir;
  }
  const float* Vb = V + ((size_t)b * L + c0) * D_MODEL + h * DH;
  for (int i4 = tid; i4 < PV_LC * (DH / 4); i4 += 256) {
    int l = i4 >> 4;
    int d4 = (i4 & 15) * 4;
    float4 v4 = *(const float4*)(Vb + (size_t)l * D_MODEL + d4);
    Vl[l][d4 + 0] = v4.x; Vl[l][d4 + 1] = v4.y;
    Vl[l][d4 + 2] = v4.z; Vl[l][d4 + 3] = v4.w;
  }
  __syncthreads();
  const int wave = tid >> 6, lane = tid & 63;
  constexpr int NJ = (U + 3) / 4;
  float acc[NJ] = {};
  for (int l = 0; l < PV_LC; ++l) {
    float vv = Vl[l][lane];
#pragma unroll
    for (int j = 0; j < NJ; ++j) {
      int r = wave + 4 * j;
      if (r < U) acc[j] += Pl[r][l] * vv;
    }
  }
#pragma unroll
  for (int j = 0; j < NJ; ++j) {
    int r = wave + 4 * j;
    if (r < U) {
      int ml = Mtop[z * U + r];
      atomicAdd(&O[((size_t)(b * L + ml)) * D_MODEL + h * DH + lane], acc[j]);
    }
  }
}

static void run_pv(const float* P, const float* V, const float* mrow,
                   const float* lrow, const int* Mtop, float* O, int L, int U,
                   hipStream_t stream) {
  dim3 gg(L / PV_LC, 32);
  if (U == 40)      pv_kernel<40><<<gg, 256, 0, stream>>>(P, V, mrow, lrow, Mtop, O, L);
  else if (U == 35) pv_kernel<35><<<gg, 256, 0, stream>>>(P, V, mrow, lrow, Mtop, O, L);
  else              pv_kernel<64><<<gg, 256, 0, stream>>>(P, V, mrow, lrow, Mtop, O, L);
}

// post-pv: recast ONLY the selected segments fp32 -> bf16
__global__ void cast_sel_kernel(const float* __restrict__ O32,
                                const int* __restrict__ Mtop,
                                unsigned short* __restrict__ O16, int L,
                                int U) {
  int z = blockIdx.x;
  int b = z >> 3, h = z & 7;
  int t = threadIdx.x;
  int d = t & 63;
  for (int r = t >> 6; r < U; r += 4) {
    int l = Mtop[z * U + r];
    size_t off = ((size_t)(b * L + l)) * D_MODEL + h * DH + d;
    O16[off] = f2bf(O32[off]);
  }
}

// ---------------- maxpool k=3 s=2, dual fp32/bf16 out ---------------------
__global__ void maxpool_kernel(const float* __restrict__ Y,
                               float* __restrict__ X,
                               unsigned short* __restrict__ Xb, int B, int L) {
  int Lo = L / 2;
  int i = blockIdx.x * 256 + threadIdx.x;
  int total = B * Lo * D_MODEL;
  if (i >= total) return;
  int d = i % D_MODEL;
  int lp = (i / D_MODEL) % Lo;
  int b = i / (D_MODEL * Lo);
  int l0 = 2 * lp - 1;
  float m = -INFINITY;
#pragma unroll
  for (int k = 0; k < 3; ++k) {
    int l = l0 + k;
    if (l >= 0 && l < L) m = fmaxf(m, Y[((size_t)(b * L + l)) * D_MODEL + d]);
  }
  X[i] = m;
  Xb[i] = f2bf(m);
}

// ==========================================================================
extern "C" void kernel_launch(void* const* d_in, const int* in_sizes, int n_in,
                              void* d_out, int out_size, void* d_ws,
                              size_t ws_size, hipStream_t stream) {
  const float* x_enc  = (const float*)d_in[0];
  const float* emb_w  = (const float*)d_in[1];
  const float* Wq     = (const float*)d_in[2];
  const float* bq     = (const float*)d_in[3];
  const float* Wk     = (const float*)d_in[4];
  const float* bk     = (const float*)d_in[5];
  const float* Wv     = (const float*)d_in[6];
  const float* bv     = (const float*)d_in[7];
  const float* Wo     = (const float*)d_in[8];
  const float* bo     = (const float*)d_in[9];
  const float* ln1_g  = (const float*)d_in[10];
  const float* ln1_b  = (const float*)d_in[11];
  const float* ff_w1  = (const float*)d_in[12];
  const float* ff_b1  = (const float*)d_in[13];
  const float* ff_w2  = (const float*)d_in[14];
  const float* ff_b2  = (const float*)d_in[15];
  const float* ln2_g  = (const float*)d_in[16];
  const float* ln2_b  = (const float*)d_in[17];
  const float* cv_w   = (const float*)d_in[18];
  const float* cv_b   = (const float*)d_in[19];
  const float* bn_g   = (const float*)d_in[20];
  const float* bn_b   = (const float*)d_in[21];
  const float* norm_g = (const float*)d_in[22];
  const float* norm_b = (const float*)d_in[23];

  const int B = 4, L0 = 2048, EL = 3;
  const size_t SZ = (size_t)B * 2048 * 512;
  float* ws   = (float*)d_ws;
  float* xbuf = ws;
  float* ebuf = ws + SZ;   // layer0 xb16; pre-LN temp; Sbuf
  float* qbuf = ws + 2 * SZ;
  float* kbuf = ws + 3 * SZ;   // hosts k16 (bf16 K) per layer
  float* vbuf = ws + 4 * SZ;
  float* obuf = ws + 5 * SZ;   // fp32 ctx accumulation base (selected rows)
  float* sm   = ws + 6 * SZ;
  // scratch region:
  float*         d_M     = sm;                          // 65536
  int*           d_Mtop  = (int*)(sm + 65536);          // 1280
  float*         d_vmean = sm + 65536 + 1280;           // 2048
  unsigned int*  d_bmap  = (unsigned int*)(sm + 65536 + 1280 + 2048);  // 2048
  unsigned short* qred16 = (unsigned short*)(sm + 65536 + 1280 + 2048 + 2048);
  float*         d_mrow  = sm + 136448;                 // 2048
  float*         d_lrow  = sm + 138496;                 // 2048
  // pre-cast bf16 weights region at ws + 6SZ + 160000 floats
  unsigned short* wgt  = (unsigned short*)(ws + 6 * SZ + 160000);
  unsigned short* qkvw = wgt;                    // EL x [Wq;Wk;Wv] (786432 ea)
  unsigned short* wof  = wgt + 3 * 786432;       // [wow | w1w | w2w]
  unsigned short* wow  = wof;
  unsigned short* w1w  = wof + 786432;
  unsigned short* w2w  = wof + 2 * 786432;
  unsigned short* cvw2 = wof + 3 * 786432;       // 2 x 786432 (k*512+c order)

  float* Sbuf = ebuf;
  const float inv_s = 1.0f / sqrtf(1.0f + 1e-5f);

  // ---- ALL upfront weight casts: ONE dispatch ----
  cast_all_kernel<<<10752, 256, 0, stream>>>(Wq, Wk, Wv, qkvw, Wo, ff_w1,
                                             ff_w2, wof, cv_w, cvw2);

  // layer-0 x bf16 fused into embed (-> ebuf)
  embed_kernel<<<ceil_div(B * L0 * D_MODEL, 256), 256, 0, stream>>>(
      x_enc, emb_w, xbuf, (unsigned short*)ebuf, B, L0);
  unsigned short* xb16 = (unsigned short*)ebuf;  // current layer's bf16 x

  int L = L0;
  int log2L = 11;
  for (int i = 0; i < EL; ++i) {
    const int M_ = B * L;
    int c = 5 * (int)ceil(log((double)L));
    int U = c < L ? c : L;
    int words = L / 32;
    unsigned short* k16 = (unsigned short*)kbuf;

    // QKV fused GEMM (64^2 tile, N=1536)
    qkv_gemm_kernel<<<24 * (M_ / 64), 256, 0, stream>>>(
        xb16, qkvw + (size_t)i * 786432, bq + i * 512, bk + i * 512,
        bv + i * 512, qbuf, vbuf, k16, M_, 512);

    uint32_t lk0, lk1, k20, k21;
    threefry2x32(0u, 42u, 0u, (uint32_t)i, &lk0, &lk1);
    threefry2x32(lk0, lk1, 0u, 1u, &k20, &k21);

    // fused idx + gather-dot + M reduce (+vmean zero in block 0)
    sparse_qk_fused_kernel<<<B * L, 256, 0, stream>>>(qbuf, k16, d_M, d_vmean,
                                                      B, L, U, k20, k21);
    // topk + bitmap + qred gather + vmean partial (merged dispatch)
    run_topk(d_M, qbuf, vbuf, d_vmean, d_Mtop, d_bmap, qred16, L, U, B,
             stream);

    // scores (MFMA) + ctx fill, merged (Q dead after topk's gather)
    unsigned short* ab16 = (unsigned short*)qbuf;
    {
      int nS = (L / 64) * B * NH;
      int nF = ceil_div(B * L * D_MODEL / 4, 256);
      scores_fill_kernel<<<nS + nF, 256, 0, stream>>>(
          qred16, k16, Sbuf, d_vmean, d_bmap, ab16, obuf, B, L, U, words, nS);
    }

    run_stats(Sbuf, d_mrow, d_lrow, L, U, stream);
    run_pv(Sbuf, vbuf, d_mrow, d_lrow, d_Mtop, obuf, L, U, stream);
    // recast selected segments into the bf16 ctx
    cast_sel_kernel<<<B * NH, 256, 0, stream>>>(obuf, d_Mtop, ab16, L, U);

    // O-proj (+residual) -> ebuf fp32
    run_bgemm<2, 1>(ab16, wow + (size_t)i * 262144, bo + i * 512, xbuf,
                    nullptr, nullptr, ebuf, nullptr, M_, 512, 512, 0.f,
                    stream);
    // ln1 dual-writes x fp32 + bf16 (FF1 A input) -> qbuf shorts
    ln_dual_kernel<<<M_, 256, 0, stream>>>(ebuf, ln1_g + i * 512,
                                           ln1_b + i * 512, xbuf, ab16);

    // FF1: bf16-only output -> obuf shorts
    unsigned short* ff1b16 = (unsigned short*)obuf;
    run_bgemm<1, 2>(ab16, w1w + (size_t)i * 262144, ff_b1 + i * 512, nullptr,
                    nullptr, nullptr, nullptr, ff1b16, M_, 512, 512, 0.f,
                    stream);
    // FF2 (+residual) -> ebuf fp32
    run_bgemm<2, 1>(ff1b16, w2w + (size_t)i * 262144, ff_b2 + i * 512, xbuf,
                    nullptr, nullptr, ebuf, nullptr, M_, 512, 512, 0.f,
                    stream);

    if (i < EL - 1) {
      // ln2 dual: fp32 -> xbuf, bf16 -> qbuf (conv GEMM A)
      unsigned short* xln16 = (unsigned short*)qbuf;
      ln_dual_kernel<<<M_, 256, 0, stream>>>(ebuf, ln2_g + i * 512,
                                             ln2_b + i * 512, xbuf, xln16);
      // conv distill as shifted-K GEMM
      conv_gemm_kernel<<<8 * (M_ / 64), 256, 0, stream>>>(
          xln16, cvw2 + (size_t)i * 786432, cv_b + i * 512, bn_g + i * 512,
          bn_b + i * 512, ebuf, M_, L, log2L, inv_s);
      // maxpool dual-writes next-layer x fp32 + bf16 @ vbuf tail
      xb16 = (unsigned short*)vbuf + 6291456;  // byte offset 12.6MB
      maxpool_kernel<<<ceil_div(B * (L / 2) * D_MODEL, 256), 256, 0, stream>>>(
          ebuf, xbuf, xb16, B, L);
      L /= 2;
      log2L -= 1;
    } else {
      ln_kernel<<<M_, 256, 0, stream>>>(ebuf, ln2_g + i * 512,
                                        ln2_b + i * 512, xbuf);
    }
  }

  ln_kernel<<<B * L, 256, 0, stream>>>(xbuf, norm_g, norm_b, (float*)d_out);
}